// Round 1
// baseline (16803.793 us; speedup 1.0000x reference)
//
#include <hip/hip_runtime.h>
#include <math.h>

#define Bn 16
#define Cn 256
#define CQn 32
#define CMn 128
#define Hn 96
#define Wn 96
#define Nn 9216
#define PIXn 147456

__device__ inline float waveSum(float v){
#pragma unroll
  for(int o=32;o;o>>=1) v += __shfl_down(v,o,64);
  return v;
}
__device__ inline float waveMax(float v){
#pragma unroll
  for(int o=32;o;o>>=1) v = fmaxf(v,__shfl_down(v,o,64));
  return v;
}

// out[bc] = (weighted ? sum_n x[bc,n]*wt[b,n] : mean_n x[bc,n])
__global__ void k_colreduce(const float* __restrict__ x, const float* __restrict__ wt,
                            float* __restrict__ out, int weighted){
  int bc = blockIdx.x;
  int b  = bc / Cn;
  const float* p  = x  + (size_t)bc*Nn;
  const float* wp = wt + (size_t)b*Nn;
  float s = 0.f;
  for(int i=threadIdx.x;i<Nn;i+=256)
    s += weighted ? p[i]*wp[i] : p[i];
  __shared__ float r4[4];
  s = waveSum(s);
  if((threadIdx.x&63)==0) r4[threadIdx.x>>6]=s;
  __syncthreads();
  if(threadIdx.x==0){
    float tot=r4[0]+r4[1]+r4[2]+r4[3];
    out[bc] = weighted ? tot : tot*(1.f/Nn);
  }
}

// per-batch: avg[cm]=sum_c wql[cm,c]*xmean[b,c]; wvec[b,c]=sum_cm avg[cm]*wvl[cm,c]
__global__ void k_small1(const float* __restrict__ xmean, const float* __restrict__ wql,
                         const float* __restrict__ wvl, float* __restrict__ wvec){
  int b=blockIdx.x, t=threadIdx.x;
  __shared__ float xm[Cn];
  __shared__ float av[CMn];
  xm[t] = xmean[b*Cn+t];
  __syncthreads();
  if(t<CMn){
    float s=0.f;
    for(int c=0;c<Cn;c++) s += wql[t*Cn+c]*xm[c];
    av[t]=s;
  }
  __syncthreads();
  float s=0.f;
  for(int m=0;m<CMn;m++) s += av[m]*wvl[m*Cn+t];
  wvec[b*Cn+t]=s;
}

// mask_raw[b,n]=sum_c wqr[c]*x ; ctxs_raw[b,n]=sum_c wvec[b,c]*x
__global__ void k_pixdot2(const float* __restrict__ x, const float* __restrict__ wqr,
                          const float* __restrict__ wvec, float* __restrict__ mraw,
                          float* __restrict__ craw){
  int p = blockIdx.x*256 + threadIdx.x;
  int b = p / Nn, n = p % Nn;
  const float* xp = x + (size_t)b*Cn*Nn + n;
  const float* wv = wvec + b*Cn;
  float s1=0.f, s2=0.f;
  for(int c=0;c<Cn;c++){
    float xv = xp[(size_t)c*Nn];
    s1 += wqr[c]*xv;
    s2 += wv[c]*xv;
  }
  mraw[p]=s1; craw[p]=s2;
}

// per-batch softmax over Nn; mode1 applies sigmoid to the softmax value
__global__ void k_softmax_n(const float* __restrict__ in, float* __restrict__ out, int mode){
  int b=blockIdx.x, tid=threadIdx.x, lane=tid&63, wid=tid>>6;
  const float* p = in + (size_t)b*Nn;
  __shared__ float red[16];
  __shared__ float bc2[2];
  float mx=-3e38f;
  for(int i=tid;i<Nn;i+=1024) mx=fmaxf(mx,p[i]);
  mx = waveMax(mx);
  if(lane==0) red[wid]=mx;
  __syncthreads();
  if(tid==0){ float m=red[0]; for(int i=1;i<16;i++) m=fmaxf(m,red[i]); bc2[0]=m; }
  __syncthreads();
  mx=bc2[0];
  float s=0.f;
  for(int i=tid;i<Nn;i+=1024) s+=expf(p[i]-mx);
  s = waveSum(s);
  __syncthreads();
  if(lane==0) red[wid]=s;
  __syncthreads();
  if(tid==0){ float t=0.f; for(int i=0;i<16;i++) t+=red[i]; bc2[1]=t; }
  __syncthreads();
  float inv=1.f/bc2[1];
  for(int i=tid;i<Nn;i+=1024){
    float e=expf(p[i]-mx)*inv;
    out[(size_t)b*Nn+i] = mode ? 1.f/(1.f+expf(-e)) : e;
  }
}

// per-batch: ctx[cm]=sum_c wvr[cm,c]*xw[b,c]; g1[b,o]=sigmoid(bup[o]+sum_cm wup[o,cm]*ctx[cm])
__global__ void k_small2(const float* __restrict__ xw, const float* __restrict__ wvr,
                         const float* __restrict__ wup, const float* __restrict__ bup,
                         float* __restrict__ g1){
  int b=blockIdx.x, t=threadIdx.x;
  __shared__ float xs[Cn];
  __shared__ float cx[CMn];
  xs[t]=xw[b*Cn+t];
  __syncthreads();
  if(t<CMn){
    float s=0.f;
    for(int c=0;c<Cn;c++) s += wvr[t*Cn+c]*xs[c];
    cx[t]=s;
  }
  __syncthreads();
  float s=bup[t];
  for(int m=0;m<CMn;m++) s += wup[t*CMn+m]*cx[m];
  g1[b*Cn+t]=1.f/(1.f+expf(-s));
}

// t1 = x * g1[b,c]; t2 = x * m2[b,n]
__global__ void k_gates(const float* __restrict__ x, const float* __restrict__ g1,
                        const float* __restrict__ m2, float* __restrict__ t1,
                        float* __restrict__ t2){
  size_t i = (size_t)blockIdx.x*256 + threadIdx.x;
  int n  = (int)(i % Nn);
  int bc = (int)(i / Nn);
  int b  = bc / Cn;
  float xv = x[i];
  t1[i] = xv * g1[bc];
  t2[i] = xv * m2[(size_t)b*Nn + n];
}

__global__ void k_add(float* __restrict__ a, const float* __restrict__ b){
  size_t i = (size_t)blockIdx.x*256 + threadIdx.x;
  a[i] += b[i];
}

// y[b,o,n] = bias[o] + sum_c Wm[o,c]*x[b,c,n]   (tiled)
template<int OT, int NT>
__global__ void k_conv1x1(const float* __restrict__ x, const float* __restrict__ Wm,
                          const float* __restrict__ bias, float* __restrict__ y, int O){
  const int TN = NT/4;               // threads along n
  int b  = blockIdx.z;
  int o0 = blockIdx.y*OT, n0 = blockIdx.x*NT;
  __shared__ float Xs[16][NT];
  __shared__ float Ws[OT][17];
  int to = threadIdx.x / TN;
  int tn = threadIdx.x % TN;
  float acc[4][4] = {};
  for(int c0=0;c0<Cn;c0+=16){
    for(int idx=threadIdx.x; idx<16*NT; idx+=256){
      int cc=idx/NT, nn=idx%NT;
      Xs[cc][nn] = x[(size_t)(b*Cn + c0+cc)*Nn + n0+nn];
    }
    for(int idx=threadIdx.x; idx<OT*16; idx+=256){
      int oo=idx/16, cc=idx%16;
      Ws[oo][cc] = Wm[(o0+oo)*Cn + c0+cc];
    }
    __syncthreads();
    for(int cc=0;cc<16;cc++){
      float a[4], bb[4];
#pragma unroll
      for(int i=0;i<4;i++) a[i]=Ws[to*4+i][cc];
#pragma unroll
      for(int j=0;j<4;j++) bb[j]=Xs[cc][tn*4+j];
#pragma unroll
      for(int i=0;i<4;i++)
#pragma unroll
        for(int j=0;j<4;j++) acc[i][j] += a[i]*bb[j];
    }
    __syncthreads();
  }
  for(int i=0;i<4;i++){
    int o=o0+to*4+i;
    float bs = bias ? bias[o] : 0.f;
    for(int j=0;j<4;j++)
      y[(size_t)(b*O + o)*Nn + n0+tn*4+j] = acc[i][j] + bs;
  }
}

// e_h: block per (b,w); att[b,h,w,k] = sum_c q[b,c,h,w]*k[b,c,k,w], diag -> -1e30
__global__ void k_eh(const float* __restrict__ q, const float* __restrict__ k,
                     float* __restrict__ att){
  int bw=blockIdx.x, b=bw/Wn, w=bw%Wn;
  __shared__ float Qc[CQn][Hn+1];
  __shared__ float Kc[CQn][Hn+1];
  for(int idx=threadIdx.x; idx<CQn*Hn; idx+=256){
    int c=idx/Hn, hh=idx%Hn;
    size_t base = ((size_t)(b*CQn+c)*Hn + hh)*Wn + w;
    Qc[c][hh]=q[base]; Kc[c][hh]=k[base];
  }
  __syncthreads();
  for(int idx=threadIdx.x; idx<Hn*Hn; idx+=256){
    int h=idx/Hn, kk=idx%Hn;
    float s=0.f;
    for(int c=0;c<CQn;c++) s += Qc[c][h]*Kc[c][kk];
    att[((size_t)(b*Nn + h*Wn + w))*192 + kk] = (kk==h) ? -1e30f : s;
  }
}

// e_w: block per (b,h); att[b,h,w,96+j] = sum_c q[b,c,h,w]*k[b,c,h,j]
__global__ void k_ew(const float* __restrict__ q, const float* __restrict__ k,
                     float* __restrict__ att){
  int bh=blockIdx.x, b=bh/Hn, h=bh%Hn;
  __shared__ float Qr[CQn][Wn+1];
  __shared__ float Kr[CQn][Wn+1];
  for(int idx=threadIdx.x; idx<CQn*Wn; idx+=256){
    int c=idx/Wn, ww=idx%Wn;
    size_t base = ((size_t)(b*CQn+c)*Hn + h)*Wn + ww;
    Qr[c][ww]=q[base]; Kr[c][ww]=k[base];
  }
  __syncthreads();
  for(int idx=threadIdx.x; idx<Wn*Wn; idx+=256){
    int w=idx/Wn, j=idx%Wn;
    float s=0.f;
    for(int c=0;c<CQn;c++) s += Qr[c][w]*Kr[c][j];
    att[((size_t)(b*Nn + h*Wn + w))*192 + 96 + j] = s;
  }
}

// softmax over 192 entries per pixel; one wave per pixel
__global__ void k_att_softmax(float* __restrict__ att){
  int wave = threadIdx.x>>6, lane = threadIdx.x&63;
  size_t p = (size_t)blockIdx.x*4 + wave;
  float* a = att + p*192;
  float v0=a[lane], v1=a[lane+64], v2=a[lane+128];
  float mx = fmaxf(v0, fmaxf(v1,v2));
#pragma unroll
  for(int o=32;o;o>>=1) mx = fmaxf(mx, __shfl_xor(mx,o,64));
  float e0=expf(v0-mx), e1=expf(v1-mx), e2=expf(v2-mx);
  float s=e0+e1+e2;
#pragma unroll
  for(int o=32;o;o>>=1) s += __shfl_xor(s,o,64);
  float inv=1.f/s;
  a[lane]=e0*inv; a[lane+64]=e1*inv; a[lane+128]=e2*inv;
}

// out_h: block per (b,w); out = gamma*sum_k v[b,c,k,w]*A[h,k] + resid
__global__ void k_pvh(const float* __restrict__ v, const float* __restrict__ att,
                      const float* __restrict__ resid, float* __restrict__ out,
                      const float* __restrict__ gp){
  int bw=blockIdx.x, b=bw/Wn, w=bw%Wn;
  float gm = gp[0];
  __shared__ float A[Hn][Hn+1];
  __shared__ float Vc[64][Hn+1];
  for(int idx=threadIdx.x; idx<Hn*Hn; idx+=256){
    int h=idx/Hn, kk=idx%Hn;
    A[h][kk] = att[((size_t)(b*Nn + h*Wn + w))*192 + kk];
  }
  int c  = threadIdx.x & 63;
  int hg = threadIdx.x >> 6;
  for(int c0=0;c0<Cn;c0+=64){
    __syncthreads();
    for(int idx=threadIdx.x; idx<64*Hn; idx+=256){
      int cc=idx/Hn, kk=idx%Hn;
      Vc[cc][kk] = v[((size_t)(b*Cn + c0+cc)*Hn + kk)*Wn + w];
    }
    __syncthreads();
    for(int h=hg; h<Hn; h+=4){
      float s=0.f;
      for(int kk=0;kk<Hn;kk++) s += Vc[c][kk]*A[h][kk];
      size_t oidx = ((size_t)(b*Cn + c0+c)*Hn + h)*Wn + w;
      out[oidx] = gm*s + resid[oidx];
    }
  }
}

// out_w: block per (b,h); out += gamma*sum_j v[b,c,h,j]*A[w,j]
__global__ void k_pvw(const float* __restrict__ v, const float* __restrict__ att,
                      float* __restrict__ out, const float* __restrict__ gp){
  int bh=blockIdx.x, b=bh/Hn, h=bh%Hn;
  float gm = gp[0];
  __shared__ float A[Wn][Wn+1];
  __shared__ float Vr[64][Wn+1];
  for(int idx=threadIdx.x; idx<Wn*Wn; idx+=192){
    int w=idx/Wn, j=idx%Wn;
    A[w][j] = att[((size_t)(b*Nn + h*Wn + w))*192 + 96 + j];
  }
  int w  = threadIdx.x % 96;
  int cg = threadIdx.x / 96;
  for(int c0=0;c0<Cn;c0+=64){
    __syncthreads();
    for(int idx=threadIdx.x; idx<64*Wn; idx+=192){
      int cc=idx/Wn, j=idx%Wn;
      Vr[cc][j] = v[((size_t)(b*Cn + c0+cc)*Hn + h)*Wn + j];
    }
    __syncthreads();
    for(int cc=cg*32; cc<cg*32+32; cc++){
      float s=0.f;
      for(int j=0;j<Wn;j++) s += Vr[cc][j]*A[w][j];
      size_t oidx = ((size_t)(b*Cn + c0+cc)*Hn + h)*Wn + w;
      out[oidx] += gm*s;
    }
  }
}

extern "C" void kernel_launch(void* const* d_in, const int* in_sizes, int n_in,
                              void* d_out, int out_size, void* d_ws, size_t ws_size,
                              hipStream_t stream){
  const float* x    = (const float*)d_in[0];
  const float* wqr  = (const float*)d_in[1];
  const float* wvr  = (const float*)d_in[2];
  const float* wup  = (const float*)d_in[3];
  const float* bup  = (const float*)d_in[4];
  const float* wql  = (const float*)d_in[5];
  const float* wvl  = (const float*)d_in[6];
  const float* crwq = (const float*)d_in[7];
  const float* crbq = (const float*)d_in[8];
  const float* crwk = (const float*)d_in[9];
  const float* crbk = (const float*)d_in[10];
  const float* crwv = (const float*)d_in[11];
  const float* crbv = (const float*)d_in[12];
  const float* gma  = (const float*)d_in[13];
  float* out = (float*)d_out;

  float* ws = (float*)d_ws;
  const size_t XSZ = (size_t)Bn*Cn*Nn;       // 37,748,736
  const size_t QSZ = (size_t)Bn*CQn*Nn;      // 4,718,592
  float* W1  = ws;  ws += XSZ;
  float* Vb  = ws;  ws += XSZ;
  float* Qb  = ws;  ws += QSZ;
  float* Kb  = ws;  ws += QSZ;
  float* ATT = ws;  ws += (size_t)PIXn*192;  // 28,311,552
  float* xmean = ws; ws += Bn*Cn;
  float* wvec  = ws; ws += Bn*Cn;
  float* xw    = ws; ws += Bn*Cn;
  float* g1    = ws; ws += Bn*Cn;
  float* mraw  = ws; ws += PIXn;
  float* maskb = ws; ws += PIXn;
  float* craw  = ws; ws += PIXn;
  float* m2    = ws; ws += PIXn;
  float* W2 = out;   // t2 / y2 lives in d_out until the final cross

  // ---- gating modules (algebraically reduced) ----
  k_colreduce<<<Bn*Cn,256,0,stream>>>(x, x, xmean, 0);
  k_small1<<<Bn,256,0,stream>>>(xmean, wql, wvl, wvec);
  k_pixdot2<<<PIXn/256,256,0,stream>>>(x, wqr, wvec, mraw, craw);
  k_softmax_n<<<Bn,1024,0,stream>>>(mraw, maskb, 0);
  k_softmax_n<<<Bn,1024,0,stream>>>(craw, m2, 1);
  k_colreduce<<<Bn*Cn,256,0,stream>>>(x, maskb, xw, 1);
  k_small2<<<Bn,256,0,stream>>>(xw, wvr, wup, bup, g1);
  k_gates<<<147456,256,0,stream>>>(x, g1, m2, W1, W2);

  auto cross = [&](const float* t, float* o){
    k_conv1x1<32,128><<<dim3(Nn/128,1,Bn),256,0,stream>>>(t, crwq, crbq, Qb, CQn);
    k_conv1x1<32,128><<<dim3(Nn/128,1,Bn),256,0,stream>>>(t, crwk, crbk, Kb, CQn);
    k_conv1x1<64,64><<<dim3(Nn/64,Cn/64,Bn),256,0,stream>>>(t, crwv, crbv, Vb, Cn);
    k_eh<<<Bn*Wn,256,0,stream>>>(Qb,Kb,ATT);
    k_ew<<<Bn*Hn,256,0,stream>>>(Qb,Kb,ATT);
    k_att_softmax<<<PIXn/4,256,0,stream>>>(ATT);
    k_pvh<<<Bn*Wn,256,0,stream>>>(Vb,ATT,t,o,gma);
    k_pvw<<<Bn*Hn,192,0,stream>>>(Vb,ATT,o,gma);
  };

  cross(W1, W1);          // y1 = cross(t1), in place
  cross(W2, W2);          // y2 = cross(t2), in place (in d_out)
  k_add<<<147456,256,0,stream>>>(W1, W2);   // W1 = y1 + y2
  cross(W1, out);         // final
}

// Round 2
// 3220.037 us; speedup vs baseline: 5.2185x; 5.2185x over previous
//
#include <hip/hip_runtime.h>
#include <math.h>

#define Bn 16
#define Cn 256
#define CQn 32
#define CMn 128
#define Hn 96
#define Wn 96
#define Nn 9216
#define PIXn 147456

__device__ inline float waveSum(float v){
#pragma unroll
  for(int o=32;o;o>>=1) v += __shfl_down(v,o,64);
  return v;
}
__device__ inline float waveMax(float v){
#pragma unroll
  for(int o=32;o;o>>=1) v = fmaxf(v,__shfl_down(v,o,64));
  return v;
}

// ---------------- gating (unchanged from passing round 1) ----------------

__global__ void k_colreduce(const float* __restrict__ x, const float* __restrict__ wt,
                            float* __restrict__ out, int weighted){
  int bc = blockIdx.x;
  int b  = bc / Cn;
  const float* p  = x  + (size_t)bc*Nn;
  const float* wp = wt + (size_t)b*Nn;
  float s = 0.f;
  for(int i=threadIdx.x;i<Nn;i+=256)
    s += weighted ? p[i]*wp[i] : p[i];
  __shared__ float r4[4];
  s = waveSum(s);
  if((threadIdx.x&63)==0) r4[threadIdx.x>>6]=s;
  __syncthreads();
  if(threadIdx.x==0){
    float tot=r4[0]+r4[1]+r4[2]+r4[3];
    out[bc] = weighted ? tot : tot*(1.f/Nn);
  }
}

__global__ void k_small1(const float* __restrict__ xmean, const float* __restrict__ wql,
                         const float* __restrict__ wvl, float* __restrict__ wvec){
  int b=blockIdx.x, t=threadIdx.x;
  __shared__ float xm[Cn];
  __shared__ float av[CMn];
  xm[t] = xmean[b*Cn+t];
  __syncthreads();
  if(t<CMn){
    float s=0.f;
    for(int c=0;c<Cn;c++) s += wql[t*Cn+c]*xm[c];
    av[t]=s;
  }
  __syncthreads();
  float s=0.f;
  for(int m=0;m<CMn;m++) s += av[m]*wvl[m*Cn+t];
  wvec[b*Cn+t]=s;
}

__global__ void k_pixdot2(const float* __restrict__ x, const float* __restrict__ wqr,
                          const float* __restrict__ wvec, float* __restrict__ mraw,
                          float* __restrict__ craw){
  int p = blockIdx.x*256 + threadIdx.x;
  int b = p / Nn, n = p % Nn;
  const float* xp = x + (size_t)b*Cn*Nn + n;
  const float* wv = wvec + b*Cn;
  float s1=0.f, s2=0.f;
  for(int c=0;c<Cn;c++){
    float xv = xp[(size_t)c*Nn];
    s1 += wqr[c]*xv;
    s2 += wv[c]*xv;
  }
  mraw[p]=s1; craw[p]=s2;
}

__global__ void k_softmax_n(const float* __restrict__ in, float* __restrict__ out, int mode){
  int b=blockIdx.x, tid=threadIdx.x, lane=tid&63, wid=tid>>6;
  const float* p = in + (size_t)b*Nn;
  __shared__ float red[16];
  __shared__ float bc2[2];
  float mx=-3e38f;
  for(int i=tid;i<Nn;i+=1024) mx=fmaxf(mx,p[i]);
  mx = waveMax(mx);
  if(lane==0) red[wid]=mx;
  __syncthreads();
  if(tid==0){ float m=red[0]; for(int i=1;i<16;i++) m=fmaxf(m,red[i]); bc2[0]=m; }
  __syncthreads();
  mx=bc2[0];
  float s=0.f;
  for(int i=tid;i<Nn;i+=1024) s+=expf(p[i]-mx);
  s = waveSum(s);
  __syncthreads();
  if(lane==0) red[wid]=s;
  __syncthreads();
  if(tid==0){ float t=0.f; for(int i=0;i<16;i++) t+=red[i]; bc2[1]=t; }
  __syncthreads();
  float inv=1.f/bc2[1];
  for(int i=tid;i<Nn;i+=1024){
    float e=expf(p[i]-mx)*inv;
    out[(size_t)b*Nn+i] = mode ? 1.f/(1.f+expf(-e)) : e;
  }
}

__global__ void k_small2(const float* __restrict__ xw, const float* __restrict__ wvr,
                         const float* __restrict__ wup, const float* __restrict__ bup,
                         float* __restrict__ g1){
  int b=blockIdx.x, t=threadIdx.x;
  __shared__ float xs[Cn];
  __shared__ float cx[CMn];
  xs[t]=xw[b*Cn+t];
  __syncthreads();
  if(t<CMn){
    float s=0.f;
    for(int c=0;c<Cn;c++) s += wvr[t*Cn+c]*xs[c];
    cx[t]=s;
  }
  __syncthreads();
  float s=bup[t];
  for(int m=0;m<CMn;m++) s += wup[t*CMn+m]*cx[m];
  g1[b*Cn+t]=1.f/(1.f+expf(-s));
}

__global__ void k_gates(const float* __restrict__ x, const float* __restrict__ g1,
                        const float* __restrict__ m2, float* __restrict__ t1,
                        float* __restrict__ t2){
  size_t i = (size_t)blockIdx.x*256 + threadIdx.x;
  int n  = (int)(i % Nn);
  int bc = (int)(i / Nn);
  int b  = bc / Cn;
  float xv = x[i];
  t1[i] = xv * g1[bc];
  t2[i] = xv * m2[(size_t)b*Nn + n];
}

__global__ void k_add(float* __restrict__ a, const float* __restrict__ b){
  size_t i = (size_t)blockIdx.x*256 + threadIdx.x;
  a[i] += b[i];
}

// ---------------- cross-attention machinery ----------------

// pack W into [320][256]: rows 0-31 wq, 32-63 wk, 64-319 wv; bias likewise
__global__ void k_pack(const float* __restrict__ wq, const float* __restrict__ bq,
                       const float* __restrict__ wk, const float* __restrict__ bk,
                       const float* __restrict__ wv, const float* __restrict__ bv,
                       float* __restrict__ Wp, float* __restrict__ bp){
  int o = blockIdx.x, t = threadIdx.x;
  const float* src; float bs;
  if(o<32){ src = wq + o*Cn; bs = bq[o]; }
  else if(o<64){ src = wk + (o-32)*Cn; bs = bk[o-32]; }
  else { src = wv + (o-64)*Cn; bs = bv[o-64]; }
  Wp[o*Cn+t] = src[t];
  if(t==0) bp[o] = bs;
}

// fused QKV GEMM: y[b,o,n] = bp[o] + sum_c Wp[o,c]*x[b,c,n]; o<64 -> Yqk, else -> Vb
__global__ __launch_bounds__(256) void k_gemm_qkv(const float* __restrict__ x,
    const float* __restrict__ Wp, const float* __restrict__ bp,
    float* __restrict__ Yqk, float* __restrict__ Vb){
  int b = blockIdx.z;
  int o0 = blockIdx.y*64, n0 = blockIdx.x*64;
  __shared__ float Ws[16][68];  // [cc][oo]  (W transposed)
  __shared__ float Xs[16][68];  // [cc][nn]
  int tid = threadIdx.x;
  int to = tid>>4, tn = tid&15;
  float acc[4][4] = {};
  for(int c0=0;c0<Cn;c0+=16){
    __syncthreads();
    {
      int oo = tid>>2, cc4 = (tid&3)*4;
      const float4 wv = *(const float4*)&Wp[(size_t)(o0+oo)*Cn + c0 + cc4];
      Ws[cc4][oo]=wv.x; Ws[cc4+1][oo]=wv.y; Ws[cc4+2][oo]=wv.z; Ws[cc4+3][oo]=wv.w;
      int cc = tid>>4, n4 = (tid&15)*4;
      const float4 xv = *(const float4*)&x[((size_t)b*Cn + c0+cc)*Nn + n0 + n4];
      *(float4*)&Xs[cc][n4] = xv;
    }
    __syncthreads();
#pragma unroll
    for(int cc=0;cc<16;cc++){
      float a[4],bb[4];
#pragma unroll
      for(int i=0;i<4;i++) a[i]=Ws[cc][to*4+i];
#pragma unroll
      for(int j=0;j<4;j++) bb[j]=Xs[cc][tn*4+j];
#pragma unroll
      for(int i=0;i<4;i++)
#pragma unroll
        for(int j=0;j<4;j++) acc[i][j]+=a[i]*bb[j];
    }
  }
#pragma unroll
  for(int i=0;i<4;i++){
    int oa = o0 + to*4 + i;
    float bs = bp[oa];
    float* dst = (oa<64) ? (Yqk + ((size_t)b*64 + oa)*Nn)
                         : (Vb + ((size_t)b*Cn + (oa-64))*Nn);
    float4 v; v.x=acc[i][0]+bs; v.y=acc[i][1]+bs; v.z=acc[i][2]+bs; v.w=acc[i][3]+bs;
    *(float4*)&dst[n0 + tn*4] = v;
  }
}

// per-plane 96x96 transpose (in-place safe: whole plane staged in LDS first)
__global__ __launch_bounds__(256) void k_transpose(const float* __restrict__ src,
                                                   float* __restrict__ dst){
  __shared__ float Ls[96][97];
  size_t base = (size_t)blockIdx.x * Nn;
  int tid = threadIdx.x;
  for(int idx=tid; idx<Nn; idx+=256)
    Ls[idx/96][idx%96] = src[base+idx];
  __syncthreads();
  for(int idx=tid; idx<Nn; idx+=256)
    dst[base+idx] = Ls[idx%96][idx/96];
}

// e_h: block (b,w); reads TRANSPOSED yt (rows along h); att[...,k] = Q.K, diag -> -1e30
__global__ __launch_bounds__(256) void k_eh(const float* __restrict__ yt,
                                            float* __restrict__ att){
  int bw = blockIdx.x; int b = bw/Wn, w = bw%Wn;
  __shared__ float Qc[CQn][97], Kc[CQn][97];
  int tid = threadIdx.x;
  for(int idx=tid; idx<CQn*Hn; idx+=256){
    int c = idx/Hn, hh = idx%Hn;
    size_t base = ((size_t)b*64 + c)*Nn + (size_t)w*Hn + hh;
    Qc[c][hh] = yt[base];
    Kc[c][hh] = yt[base + (size_t)32*Nn];
  }
  __syncthreads();
  int th = tid>>4, tk = tid&15;
  float acc[6][6] = {};
  for(int c=0;c<CQn;c++){
    float qv[6], kv[6];
#pragma unroll
    for(int i=0;i<6;i++) qv[i]=Qc[c][th*6+i];
#pragma unroll
    for(int j=0;j<6;j++) kv[j]=Kc[c][tk*6+j];
#pragma unroll
    for(int i=0;i<6;i++)
#pragma unroll
      for(int j=0;j<6;j++) acc[i][j]+=qv[i]*kv[j];
  }
#pragma unroll
  for(int i=0;i<6;i++){
    int h = th*6+i;
    float* arow = att + ((size_t)b*Nn + (size_t)h*Wn + w)*192;
#pragma unroll
    for(int j=0;j<6;j++){
      int kk = tk*6+j;
      arow[kk] = (kk==h) ? -1e30f : acc[i][j];
    }
  }
}

// e_w: block (b,h); reads y (rows along w); att[...,96+j] = Q.K
__global__ __launch_bounds__(256) void k_ew(const float* __restrict__ y,
                                            float* __restrict__ att){
  int bh = blockIdx.x; int b = bh/Hn, h = bh%Hn;
  __shared__ float Qr[CQn][97], Kr[CQn][97];
  int tid = threadIdx.x;
  for(int idx=tid; idx<CQn*Wn; idx+=256){
    int c = idx/Wn, ww = idx%Wn;
    size_t base = ((size_t)b*64 + c)*Nn + (size_t)h*Wn + ww;
    Qr[c][ww] = y[base];
    Kr[c][ww] = y[base + (size_t)32*Nn];
  }
  __syncthreads();
  int tw = tid>>4, tj = tid&15;
  float acc[6][6] = {};
  for(int c=0;c<CQn;c++){
    float qv[6], kv[6];
#pragma unroll
    for(int i=0;i<6;i++) qv[i]=Qr[c][tw*6+i];
#pragma unroll
    for(int j=0;j<6;j++) kv[j]=Kr[c][tj*6+j];
#pragma unroll
    for(int i=0;i<6;i++)
#pragma unroll
      for(int j=0;j<6;j++) acc[i][j]+=qv[i]*kv[j];
  }
#pragma unroll
  for(int i=0;i<6;i++){
    int w = tw*6+i;
    float* arow = att + ((size_t)b*Nn + (size_t)h*Wn + w)*192 + 96;
#pragma unroll
    for(int j=0;j<6;j++) arow[tj*6+j] = acc[i][j];
  }
}

// softmax over 192 entries per pixel; one wave per pixel
__global__ void k_att_softmax(float* __restrict__ att){
  int wave = threadIdx.x>>6, lane = threadIdx.x&63;
  size_t p = (size_t)blockIdx.x*4 + wave;
  float* a = att + p*192;
  float v0=a[lane], v1=a[lane+64], v2=a[lane+128];
  float mx = fmaxf(v0, fmaxf(v1,v2));
#pragma unroll
  for(int o=32;o;o>>=1) mx = fmaxf(mx, __shfl_xor(mx,o,64));
  float e0=expf(v0-mx), e1=expf(v1-mx), e2=expf(v2-mx);
  float s=e0+e1+e2;
#pragma unroll
  for(int o=32;o;o>>=1) s += __shfl_xor(s,o,64);
  float inv=1.f/s;
  a[lane]=e0*inv; a[lane+64]=e1*inv; a[lane+128]=e2*inv;
}

// unified PV GEMM. Block (b,r): O[c,n] (+= resid) = gm * sum_j V[c,j]*A[n,j]
//  V rows:  V + b*256*9216 + r*96 + c*9216 (+j contiguous)
//  A rows:  att + b*9216*192 + r*arow_r + n*arow_n + aoff (+j contiguous)
//  O rows:  same addressing as V rows (n in place of j)
// pvh mode writes O over V in place (tile staged in LDS before overwrite).
__global__ __launch_bounds__(256) void k_pv(const float* __restrict__ V,
    const float* __restrict__ att, const float* __restrict__ resid,
    float* __restrict__ O, const float* __restrict__ gp,
    int arow_r, int arow_n, int aoff, int addresid){
  int bid = blockIdx.x;
  int b = bid/96, r = bid%96;
  float gm = gp[0];
  __shared__ float As[96][97];
  __shared__ float Vs[64][97];
  const float* ab = att + (size_t)b*Nn*192 + (size_t)r*arow_r + aoff;
  size_t vb = (size_t)b*Cn*Nn + (size_t)r*96;
  int tid = threadIdx.x;
  for(int idx=tid; idx<96*96; idx+=256){
    int n = idx/96, j = idx%96;
    As[n][j] = ab[(size_t)n*arow_n + j];
  }
  int to = tid>>4, tn = tid&15;
  for(int c0=0; c0<Cn; c0+=64){
    __syncthreads();
    for(int idx=tid; idx<64*96; idx+=256){
      int cc = idx/96, j = idx%96;
      Vs[cc][j] = V[vb + (size_t)(c0+cc)*Nn + j];
    }
    __syncthreads();
    float acc[4][6] = {};
    for(int k=0;k<96;k++){
      float a[4], bb[6];
#pragma unroll
      for(int i=0;i<4;i++) a[i] = Vs[to*4+i][k];
#pragma unroll
      for(int j2=0;j2<6;j2++) bb[j2] = As[tn*6+j2][k];
#pragma unroll
      for(int i=0;i<4;i++)
#pragma unroll
        for(int j2=0;j2<6;j2++) acc[i][j2] += a[i]*bb[j2];
    }
#pragma unroll
    for(int i=0;i<4;i++){
      size_t orow = vb + (size_t)(c0+to*4+i)*Nn + tn*6;
#pragma unroll
      for(int j2=0;j2<6;j2++){
        float val = gm*acc[i][j2];
        if(addresid) val += resid[orow + j2];
        O[orow + j2] = val;
      }
    }
  }
}

// out[...,h*96+w] += OT[...,w*96+h]  (per (b,c) plane, transpose-add)
__global__ __launch_bounds__(256) void k_merge(float* __restrict__ out,
                                               const float* __restrict__ OT){
  __shared__ float Ls[96][97];
  size_t base = (size_t)blockIdx.x * Nn;
  int tid = threadIdx.x;
  for(int idx=tid; idx<Nn; idx+=256)
    Ls[idx/96][idx%96] = OT[base+idx];
  __syncthreads();
  for(int idx=tid; idx<Nn; idx+=256)
    out[base+idx] += Ls[idx%96][idx/96];
}

extern "C" void kernel_launch(void* const* d_in, const int* in_sizes, int n_in,
                              void* d_out, int out_size, void* d_ws, size_t ws_size,
                              hipStream_t stream){
  const float* x    = (const float*)d_in[0];
  const float* wqr  = (const float*)d_in[1];
  const float* wvr  = (const float*)d_in[2];
  const float* wup  = (const float*)d_in[3];
  const float* bup  = (const float*)d_in[4];
  const float* wql  = (const float*)d_in[5];
  const float* wvl  = (const float*)d_in[6];
  const float* crwq = (const float*)d_in[7];
  const float* crbq = (const float*)d_in[8];
  const float* crwk = (const float*)d_in[9];
  const float* crbk = (const float*)d_in[10];
  const float* crwv = (const float*)d_in[11];
  const float* crbv = (const float*)d_in[12];
  const float* gma  = (const float*)d_in[13];
  float* out = (float*)d_out;

  float* ws = (float*)d_ws;
  const size_t XSZ  = (size_t)Bn*Cn*Nn;       // 37,748,736
  const size_t YSZ  = (size_t)Bn*64*Nn;       // 9,437,184
  float* W1   = ws;  ws += XSZ;
  float* Vb   = ws;  ws += XSZ;
  float* Yqk  = ws;  ws += YSZ;
  float* Yqkt = ws;  ws += YSZ;
  float* ATT  = ws;  ws += (size_t)PIXn*192;  // 28,311,552
  float* Wpack= ws;  ws += 320*Cn;
  float* bpack= ws;  ws += 320;
  float* xmean = ws; ws += Bn*Cn;
  float* wvec  = ws; ws += Bn*Cn;
  float* xw    = ws; ws += Bn*Cn;
  float* g1    = ws; ws += Bn*Cn;
  float* mraw  = ws; ws += PIXn;
  float* maskb = ws; ws += PIXn;
  float* craw  = ws; ws += PIXn;
  float* m2    = ws; ws += PIXn;
  float* W2 = out;   // t2 / y2 lives in d_out until the final cross

  k_pack<<<320,256,0,stream>>>(crwq,crbq,crwk,crbk,crwv,crbv,Wpack,bpack);

  // ---- gating modules (algebraically reduced) ----
  k_colreduce<<<Bn*Cn,256,0,stream>>>(x, x, xmean, 0);
  k_small1<<<Bn,256,0,stream>>>(xmean, wql, wvl, wvec);
  k_pixdot2<<<PIXn/256,256,0,stream>>>(x, wqr, wvec, mraw, craw);
  k_softmax_n<<<Bn,1024,0,stream>>>(mraw, maskb, 0);
  k_softmax_n<<<Bn,1024,0,stream>>>(craw, m2, 1);
  k_colreduce<<<Bn*Cn,256,0,stream>>>(x, maskb, xw, 1);
  k_small2<<<Bn,256,0,stream>>>(xw, wvr, wup, bup, g1);
  k_gates<<<147456,256,0,stream>>>(x, g1, m2, W1, W2);

  auto cross = [&](const float* t, float* o){
    k_gemm_qkv<<<dim3(Nn/64,5,Bn),256,0,stream>>>(t, Wpack, bpack, Yqk, Vb);
    k_transpose<<<Bn*64,256,0,stream>>>(Yqk, Yqkt);
    k_eh<<<Bn*Wn,256,0,stream>>>(Yqkt, ATT);
    k_ew<<<Bn*Hn,256,0,stream>>>(Yqk, ATT);
    k_att_softmax<<<PIXn/4,256,0,stream>>>(ATT);
    // out_w: o = gm * V.A_w^T + t   (block r = h; A rows n=w, contiguous j)
    k_pv<<<Bn*Hn,256,0,stream>>>(Vb, ATT, t, o, gma, 96*192, 192, 96, 1);
    // V -> V^T in place, then out_h^T computed in place over V^T
    k_transpose<<<Bn*Cn,256,0,stream>>>(Vb, Vb);
    k_pv<<<Bn*Wn,256,0,stream>>>(Vb, ATT, nullptr, Vb, gma, 192, 96*192, 0, 0);
    // o += (out_h^T)^T
    k_merge<<<Bn*Cn,256,0,stream>>>(o, Vb);
  };

  cross(W1, W1);          // y1 = cross(t1), in place
  cross(W2, W2);          // y2 = cross(t2), in place (in d_out)
  k_add<<<147456,256,0,stream>>>(W1, W2);   // W1 = y1 + y2
  cross(W1, out);         // final
}

// Round 4
// 1796.833 us; speedup vs baseline: 9.3519x; 1.7921x over previous
//
#include <hip/hip_runtime.h>
#include <math.h>

#define Bn 16
#define Cn 256
#define CQn 32
#define CMn 128
#define Hn 96
#define Wn 96
#define Nn 9216
#define PIXn 147456

typedef short bf8 __attribute__((ext_vector_type(8)));
typedef float f32x4 __attribute__((ext_vector_type(4)));
#define MFMA(a,b,c) __builtin_amdgcn_mfma_f32_16x16x32_bf16(a,b,c,0,0,0)

typedef unsigned short ushort_t;

__device__ inline ushort_t f2bf(float f){
  union{float f; unsigned int u;} v; v.f=f;
  unsigned int r = v.u + 0x7fffu + ((v.u>>16)&1u);
  return (ushort_t)(r>>16);
}
__device__ inline float bf2f(ushort_t s){
  union{unsigned int u; float f;} v; v.u = ((unsigned int)s)<<16;
  return v.f;
}

__device__ inline float waveSum(float v){
#pragma unroll
  for(int o=32;o;o>>=1) v += __shfl_down(v,o,64);
  return v;
}
__device__ inline float waveMax(float v){
#pragma unroll
  for(int o=32;o;o>>=1) v = fmaxf(v,__shfl_down(v,o,64));
  return v;
}

// ---------------- gating (unchanged, fp32) ----------------

__global__ void k_colreduce(const float* __restrict__ x, const float* __restrict__ wt,
                            float* __restrict__ out, int weighted){
  int bc = blockIdx.x;
  int b  = bc / Cn;
  const float* p  = x  + (size_t)bc*Nn;
  const float* wp = wt + (size_t)b*Nn;
  float s = 0.f;
  for(int i=threadIdx.x;i<Nn;i+=256)
    s += weighted ? p[i]*wp[i] : p[i];
  __shared__ float r4[4];
  s = waveSum(s);
  if((threadIdx.x&63)==0) r4[threadIdx.x>>6]=s;
  __syncthreads();
  if(threadIdx.x==0){
    float tot=r4[0]+r4[1]+r4[2]+r4[3];
    out[bc] = weighted ? tot : tot*(1.f/Nn);
  }
}

__global__ void k_small1(const float* __restrict__ xmean, const float* __restrict__ wql,
                         const float* __restrict__ wvl, float* __restrict__ wvec){
  int b=blockIdx.x, t=threadIdx.x;
  __shared__ float xm[Cn];
  __shared__ float av[CMn];
  xm[t] = xmean[b*Cn+t];
  __syncthreads();
  if(t<CMn){
    float s=0.f;
    for(int c=0;c<Cn;c++) s += wql[t*Cn+c]*xm[c];
    av[t]=s;
  }
  __syncthreads();
  float s=0.f;
  for(int m=0;m<CMn;m++) s += av[m]*wvl[m*Cn+t];
  wvec[b*Cn+t]=s;
}

__global__ void k_pixdot2(const float* __restrict__ x, const float* __restrict__ wqr,
                          const float* __restrict__ wvec, float* __restrict__ mraw,
                          float* __restrict__ craw){
  int p = blockIdx.x*256 + threadIdx.x;
  int b = p / Nn, n = p % Nn;
  const float* xp = x + (size_t)b*Cn*Nn + n;
  const float* wv = wvec + b*Cn;
  float s1=0.f, s2=0.f;
  for(int c=0;c<Cn;c++){
    float xv = xp[(size_t)c*Nn];
    s1 += wqr[c]*xv;
    s2 += wv[c]*xv;
  }
  mraw[p]=s1; craw[p]=s2;
}

__global__ void k_softmax_n(const float* __restrict__ in, float* __restrict__ out, int mode){
  int b=blockIdx.x, tid=threadIdx.x, lane=tid&63, wid=tid>>6;
  const float* p = in + (size_t)b*Nn;
  __shared__ float red[16];
  __shared__ float bc2[2];
  float mx=-3e38f;
  for(int i=tid;i<Nn;i+=1024) mx=fmaxf(mx,p[i]);
  mx = waveMax(mx);
  if(lane==0) red[wid]=mx;
  __syncthreads();
  if(tid==0){ float m=red[0]; for(int i=1;i<16;i++) m=fmaxf(m,red[i]); bc2[0]=m; }
  __syncthreads();
  mx=bc2[0];
  float s=0.f;
  for(int i=tid;i<Nn;i+=1024) s+=expf(p[i]-mx);
  s = waveSum(s);
  __syncthreads();
  if(lane==0) red[wid]=s;
  __syncthreads();
  if(tid==0){ float t=0.f; for(int i=0;i<16;i++) t+=red[i]; bc2[1]=t; }
  __syncthreads();
  float inv=1.f/bc2[1];
  for(int i=tid;i<Nn;i+=1024){
    float e=expf(p[i]-mx)*inv;
    out[(size_t)b*Nn+i] = mode ? 1.f/(1.f+expf(-e)) : e;
  }
}

__global__ void k_small2(const float* __restrict__ xw, const float* __restrict__ wvr,
                         const float* __restrict__ wup, const float* __restrict__ bup,
                         float* __restrict__ g1){
  int b=blockIdx.x, t=threadIdx.x;
  __shared__ float xs[Cn];
  __shared__ float cx[CMn];
  xs[t]=xw[b*Cn+t];
  __syncthreads();
  if(t<CMn){
    float s=0.f;
    for(int c=0;c<Cn;c++) s += wvr[t*Cn+c]*xs[c];
    cx[t]=s;
  }
  __syncthreads();
  float s=bup[t];
  for(int m=0;m<CMn;m++) s += wup[t*CMn+m]*cx[m];
  g1[b*Cn+t]=1.f/(1.f+expf(-s));
}

__global__ void k_gates(const float* __restrict__ x, const float* __restrict__ g1,
                        const float* __restrict__ m2, float* __restrict__ t1,
                        float* __restrict__ t2){
  size_t i = (size_t)blockIdx.x*256 + threadIdx.x;
  int n  = (int)(i % Nn);
  int bc = (int)(i / Nn);
  int b  = bc / Cn;
  float xv = x[i];
  t1[i] = xv * g1[bc];
  t2[i] = xv * m2[(size_t)b*Nn + n];
}

__global__ void k_add(float* __restrict__ a, const float* __restrict__ b){
  size_t i = (size_t)blockIdx.x*256 + threadIdx.x;
  a[i] += b[i];
}

// ---------------- cross-attention, MFMA ----------------

// pack W (bf16) [320][256]: rows 0-31 wq, 32-63 wk, 64-319 wv; bias fp32
__global__ void k_packb(const float* __restrict__ wq, const float* __restrict__ bq,
                        const float* __restrict__ wk, const float* __restrict__ bk,
                        const float* __restrict__ wv, const float* __restrict__ bv,
                        ushort_t* __restrict__ Wp, float* __restrict__ bp){
  int o = blockIdx.x, t = threadIdx.x;
  const float* src; float bs;
  if(o<32){ src = wq + o*Cn; bs = bq[o]; }
  else if(o<64){ src = wk + (o-32)*Cn; bs = bk[o-32]; }
  else { src = wv + (o-64)*Cn; bs = bv[o-64]; }
  Wp[o*Cn+t] = f2bf(src[t]);
  if(t==0) bp[o] = bs;
}

#define AP 40    // A-tile row pitch (ushorts): 32 k + pad
#define BP 264   // Bt row pitch: 256 c + pad

// fused QKV GEMM (MFMA): y[b,o,n] = bp[o] + sum_c Wp[o,c]*x[b,c,n], bf16 out
__global__ __launch_bounds__(256) void k_gemm_qkv(const float* __restrict__ x,
    const ushort_t* __restrict__ Wp, const float* __restrict__ bp,
    ushort_t* __restrict__ Yqk, ushort_t* __restrict__ Vb){
  __shared__ ushort_t Ws[320*AP];
  __shared__ ushort_t Bt[64*BP];
  int b  = blockIdx.y;
  int n0 = blockIdx.x*64;
  int tid = threadIdx.x, lane = tid&63, wid = tid>>6;

  // stage x-tile transposed -> Bt[n][c] bf16
  {
    const float* xb = x + (size_t)b*Cn*Nn + n0 + (tid&63);
    int cg = (tid>>6)*8;
#pragma unroll
    for(int p=0;p<8;p++){
      int c8 = p*32 + cg;
      float f0=xb[(size_t)(c8+0)*Nn], f1=xb[(size_t)(c8+1)*Nn];
      float f2=xb[(size_t)(c8+2)*Nn], f3=xb[(size_t)(c8+3)*Nn];
      float f4=xb[(size_t)(c8+4)*Nn], f5=xb[(size_t)(c8+5)*Nn];
      float f6=xb[(size_t)(c8+6)*Nn], f7=xb[(size_t)(c8+7)*Nn];
      uint4 pk;
      pk.x = (unsigned)f2bf(f0) | ((unsigned)f2bf(f1)<<16);
      pk.y = (unsigned)f2bf(f2) | ((unsigned)f2bf(f3)<<16);
      pk.z = (unsigned)f2bf(f4) | ((unsigned)f2bf(f5)<<16);
      pk.w = (unsigned)f2bf(f6) | ((unsigned)f2bf(f7)<<16);
      *(uint4*)&Bt[(tid&63)*BP + c8] = pk;
    }
  }

  f32x4 acc[5][4];
#pragma unroll
  for(int f=0;f<5;f++)
#pragma unroll
    for(int g=0;g<4;g++) acc[f][g] = (f32x4){0.f,0.f,0.f,0.f};

  for(int ki=0;ki<8;ki++){
    __syncthreads();
#pragma unroll
    for(int q=0;q<5;q++){
      int fidx = q*256 + tid;         // 8-elem unit
      int o = fidx>>2, kk = (fidx&3)*8;
      uint4 wv = *(const uint4*)&Wp[o*Cn + ki*32 + kk];
      *(uint4*)&Ws[o*AP + kk] = wv;
    }
    __syncthreads();
    bf8 bfr[4];
#pragma unroll
    for(int g=0;g<4;g++)
      bfr[g] = *(const bf8*)&Bt[(g*16 + (lane&15))*BP + ki*32 + (lane>>4)*8];
#pragma unroll
    for(int f=0;f<5;f++){
      bf8 a = *(const bf8*)&Ws[(wid*80 + f*16 + (lane&15))*AP + (lane>>4)*8];
#pragma unroll
      for(int g=0;g<4;g++) acc[f][g] = MFMA(a, bfr[g], acc[f][g]);
    }
  }

#pragma unroll
  for(int f=0;f<5;f++){
    int ob = wid*80 + f*16 + (lane>>4)*4;
#pragma unroll
    for(int i=0;i<4;i++){
      int o = ob + i;
      float bias = bp[o];
      ushort_t* dst = (o<64) ? (Yqk + ((size_t)b*64 + o)*Nn)
                             : (Vb + ((size_t)b*Cn + (o-64))*Nn);
#pragma unroll
      for(int g=0;g<4;g++)
        dst[n0 + g*16 + (lane&15)] = f2bf(acc[f][g][i] + bias);
    }
  }
}

// per-plane 96x96 bf16 transpose, in-place safe
__global__ __launch_bounds__(256) void k_transpose_b(const ushort_t* __restrict__ src,
                                                     ushort_t* __restrict__ dst){
  __shared__ ushort_t Ls[96*98];
  size_t base = (size_t)blockIdx.x * Nn;
  int tid = threadIdx.x;
  for(int e=tid*2; e<Nn; e+=512){
    unsigned int u = *(const unsigned int*)&src[base+e];
    int r=e/96, c=e%96;
    *(unsigned int*)&Ls[r*98+c] = u;
  }
  __syncthreads();
  for(int e=tid*2; e<Nn; e+=512){
    int r=e/96, c=e%96;
    unsigned int u = (unsigned int)Ls[c*98+r] | (((unsigned int)Ls[(c+1)*98+r])<<16);
    *(unsigned int*)&dst[base+e] = u;
  }
}

// unified QK^T (MFMA): block (b,r). E[m][n] = sum_c Q[c][m]*K[c][n].
// att[(b*Nn + m*pm + r*pr)*192 + aoff + n]; if diag, n==m -> -1e30.
__global__ __launch_bounds__(256) void k_e(const ushort_t* __restrict__ Y,
    float* __restrict__ att, int aoff, int diag, int pm, int pr){
  __shared__ ushort_t Qt[96*AP];
  __shared__ ushort_t Kt[96*AP];
  int bid = blockIdx.x; int b = bid/96, r = bid%96;
  int tid = threadIdx.x, lane = tid&63, wid = tid>>6;
  {
    int half = tid>>7;           // 0: Q, 1: K
    int cg   = (tid>>5)&3;       // c octet
    int l32  = tid&31;
    ushort_t* T = half ? Kt : Qt;
    const ushort_t* S = Y + ((size_t)b*64 + half*32 + cg*8)*Nn + (size_t)r*96;
#pragma unroll
    for(int p=0;p<3;p++){
      int sp = p*32 + l32;
      unsigned e0=S[(size_t)0*Nn+sp], e1=S[(size_t)1*Nn+sp];
      unsigned e2=S[(size_t)2*Nn+sp], e3=S[(size_t)3*Nn+sp];
      unsigned e4=S[(size_t)4*Nn+sp], e5=S[(size_t)5*Nn+sp];
      unsigned e6=S[(size_t)6*Nn+sp], e7=S[(size_t)7*Nn+sp];
      uint4 pk;
      pk.x = e0 | (e1<<16); pk.y = e2 | (e3<<16);
      pk.z = e4 | (e5<<16); pk.w = e6 | (e7<<16);
      *(uint4*)&T[sp*AP + cg*8] = pk;
    }
  }
  __syncthreads();
  int mb = (wid>>1)*48, nb = (wid&1)*48;
  const f32x4 z4 = {0.f,0.f,0.f,0.f};
  f32x4 acc[3][3];
  bf8 a[3], bb[3];
#pragma unroll
  for(int f=0;f<3;f++) a[f] = *(const bf8*)&Qt[(mb+f*16+(lane&15))*AP + (lane>>4)*8];
#pragma unroll
  for(int g=0;g<3;g++) bb[g] = *(const bf8*)&Kt[(nb+g*16+(lane&15))*AP + (lane>>4)*8];
#pragma unroll
  for(int f=0;f<3;f++)
#pragma unroll
    for(int g=0;g<3;g++) acc[f][g] = MFMA(a[f], bb[g], z4);
#pragma unroll
  for(int f=0;f<3;f++)
#pragma unroll
    for(int i=0;i<4;i++){
      int m = mb + f*16 + (lane>>4)*4 + i;
      float* arow = att + ((size_t)b*Nn + (size_t)m*pm + (size_t)r*pr)*192 + aoff;
#pragma unroll
      for(int g=0;g<3;g++){
        int n = nb + g*16 + (lane&15);
        arow[n] = (diag && n==m) ? -1e30f : acc[f][g][i];
      }
    }
}

// softmax over 192 per pixel (fp32, in place)
__global__ void k_att_softmax(float* __restrict__ att){
  int wave = threadIdx.x>>6, lane = threadIdx.x&63;
  size_t p = (size_t)blockIdx.x*4 + wave;
  float* a = att + p*192;
  float v0=a[lane], v1=a[lane+64], v2=a[lane+128];
  float mx = fmaxf(v0, fmaxf(v1,v2));
#pragma unroll
  for(int o=32;o;o>>=1) mx = fmaxf(mx, __shfl_xor(mx,o,64));
  float e0=expf(v0-mx), e1=expf(v1-mx), e2=expf(v2-mx);
  float s=e0+e1+e2;
#pragma unroll
  for(int o=32;o;o>>=1) s += __shfl_xor(s,o,64);
  float inv=1.f/s;
  a[lane]=e0*inv; a[lane+64]=e1*inv; a[lane+128]=e2*inv;
}

#define SP 104   // att-tile row pitch

// PV (MFMA). Block (b,r): O[c][n] = gm * sum_j V[c][r*96+j] * A[n][j]
// mode 0 (pvw): A[n][j] = att[(b*Nn + r*96 + n)*192 + 96 + j]; Of = val + resid (fp32)
// mode 1 (pvh): A[n][j] = att[(b*Nn + n*96 + r)*192 + j];      Ob = bf16(val), in place over V
__global__ __launch_bounds__(256) void k_pv(const ushort_t* __restrict__ V,
    const float* __restrict__ att, const float* __restrict__ resid,
    float* __restrict__ Of, ushort_t* Ob,
    const float* __restrict__ gp, int mode){
  __shared__ ushort_t As[96*SP];
  int bid = blockIdx.x; int b = bid/96, r = bid%96;
  float gm = gp[0];
  int tid = threadIdx.x, lane = tid&63, wid = tid>>6;
  const float* ab = att + (size_t)b*Nn*192
                  + (mode ? (size_t)r*192 : (size_t)r*96*192 + 96);
  size_t arow_n = mode ? (size_t)96*192 : (size_t)192;
  for(int e=tid*4; e<96*96; e+=1024){
    int n = e/96, j = e%96;
    float4 v = *(const float4*)&ab[(size_t)n*arow_n + j];
    uint2 pk;
    pk.x = (unsigned)f2bf(v.x) | ((unsigned)f2bf(v.y)<<16);
    pk.y = (unsigned)f2bf(v.z) | ((unsigned)f2bf(v.w)<<16);
    *(uint2*)&As[n*SP + j] = pk;
  }
  __syncthreads();
  size_t vbase = (size_t)b*Cn*Nn + (size_t)r*96;
  f32x4 acc[4][6];
#pragma unroll
  for(int f=0;f<4;f++)
#pragma unroll
    for(int g=0;g<6;g++) acc[f][g] = (f32x4){0.f,0.f,0.f,0.f};
#pragma unroll
  for(int j0=0;j0<96;j0+=32){
    bf8 bfr[6];
#pragma unroll
    for(int g=0;g<6;g++)
      bfr[g] = *(const bf8*)&As[(g*16+(lane&15))*SP + j0 + (lane>>4)*8];
#pragma unroll
    for(int f=0;f<4;f++){
      bf8 a = *(const bf8*)&V[vbase + (size_t)(wid*64 + f*16 + (lane&15))*Nn
                              + j0 + (lane>>4)*8];
#pragma unroll
      for(int g=0;g<6;g++) acc[f][g] = MFMA(a, bfr[g], acc[f][g]);
    }
  }
#pragma unroll
  for(int f=0;f<4;f++){
    int cb = wid*64 + f*16 + (lane>>4)*4;
#pragma unroll
    for(int i=0;i<4;i++){
      size_t row = vbase + (size_t)(cb+i)*Nn;
#pragma unroll
      for(int g=0;g<6;g++){
        int n = g*16 + (lane&15);
        float val = gm*acc[f][g][i];
        if(mode==0) Of[row+n] = val + resid[row+n];
        else        Ob[row+n] = f2bf(val);
      }
    }
  }
}

// out[b,c,h,w] += bf2f(OT[b,c,w,h])  (per-plane transpose-add)
__global__ __launch_bounds__(256) void k_merge(float* __restrict__ out,
                                               const ushort_t* __restrict__ OT){
  __shared__ ushort_t Ls[96*98];
  size_t base = (size_t)blockIdx.x * Nn;
  int tid = threadIdx.x;
  for(int e=tid*2; e<Nn; e+=512){
    unsigned int u = *(const unsigned int*)&OT[base+e];
    int r=e/96, c=e%96;
    *(unsigned int*)&Ls[r*98+c] = u;
  }
  __syncthreads();
  for(int e=tid*4; e<Nn; e+=1024){
    int r=e/96, c=e%96;
    float4 o = *(float4*)&out[base+e];
    o.x += bf2f(Ls[(c+0)*98+r]); o.y += bf2f(Ls[(c+1)*98+r]);
    o.z += bf2f(Ls[(c+2)*98+r]); o.w += bf2f(Ls[(c+3)*98+r]);
    *(float4*)&out[base+e] = o;
  }
}

extern "C" void kernel_launch(void* const* d_in, const int* in_sizes, int n_in,
                              void* d_out, int out_size, void* d_ws, size_t ws_size,
                              hipStream_t stream){
  const float* x    = (const float*)d_in[0];
  const float* wqr  = (const float*)d_in[1];
  const float* wvr  = (const float*)d_in[2];
  const float* wup  = (const float*)d_in[3];
  const float* bup  = (const float*)d_in[4];
  const float* wql  = (const float*)d_in[5];
  const float* wvl  = (const float*)d_in[6];
  const float* crwq = (const float*)d_in[7];
  const float* crbq = (const float*)d_in[8];
  const float* crwk = (const float*)d_in[9];
  const float* crbk = (const float*)d_in[10];
  const float* crwv = (const float*)d_in[11];
  const float* crbv = (const float*)d_in[12];
  const float* gma  = (const float*)d_in[13];
  float* out = (float*)d_out;

  const size_t XSZ = (size_t)Bn*Cn*Nn;    // 37,748,736
  const size_t YSZ = (size_t)Bn*64*Nn;    // 9,437,184
  char* wsb = (char*)d_ws;
  float*    W1   = (float*)wsb;    wsb += XSZ*4;
  ushort_t* Vb   = (ushort_t*)wsb; wsb += XSZ*2;
  ushort_t* Yqk  = (ushort_t*)wsb; wsb += YSZ*2;
  ushort_t* Yqkt = (ushort_t*)wsb; wsb += YSZ*2;
  float*    ATT  = (float*)wsb;    wsb += (size_t)PIXn*192*4;
  ushort_t* Wpb  = (ushort_t*)wsb; wsb += 320*Cn*2;
  float*    bp   = (float*)wsb;    wsb += 320*4;
  float*    xmean= (float*)wsb;    wsb += Bn*Cn*4;
  float*    wvec = (float*)wsb;    wsb += Bn*Cn*4;
  float*    xw   = (float*)wsb;    wsb += Bn*Cn*4;
  float*    g1   = (float*)wsb;    wsb += Bn*Cn*4;
  float*    mraw = (float*)wsb;    wsb += (size_t)PIXn*4;
  float*    maskb= (float*)wsb;    wsb += (size_t)PIXn*4;
  float*    craw = (float*)wsb;    wsb += (size_t)PIXn*4;
  float*    m2   = (float*)wsb;    wsb += (size_t)PIXn*4;
  float* W2 = out;   // t2 / y2 lives in d_out until the final cross

  k_packb<<<320,256,0,stream>>>(crwq,crbq,crwk,crbk,crwv,crbv,Wpb,bp);

  // ---- gating modules (algebraically reduced) ----
  k_colreduce<<<Bn*Cn,256,0,stream>>>(x, x, xmean, 0);
  k_small1<<<Bn,256,0,stream>>>(xmean, wql, wvl, wvec);
  k_pixdot2<<<PIXn/256,256,0,stream>>>(x, wqr, wvec, mraw, craw);
  k_softmax_n<<<Bn,1024,0,stream>>>(mraw, maskb, 0);
  k_softmax_n<<<Bn,1024,0,stream>>>(craw, m2, 1);
  k_colreduce<<<Bn*Cn,256,0,stream>>>(x, maskb, xw, 1);
  k_small2<<<Bn,256,0,stream>>>(xw, wvr, wup, bup, g1);
  k_gates<<<147456,256,0,stream>>>(x, g1, m2, W1, W2);

  auto cross = [&](const float* t, float* o){
    k_gemm_qkv<<<dim3(Nn/64,Bn),256,0,stream>>>(t, Wpb, bp, Yqk, Vb);
    k_transpose_b<<<Bn*64,256,0,stream>>>(Yqk, Yqkt);
    k_e<<<Bn*96,256,0,stream>>>(Yqkt, ATT, 0, 1, 96, 1);   // e_h (m=h, r=w)
    k_e<<<Bn*96,256,0,stream>>>(Yqk,  ATT, 96, 0, 1, 96);  // e_w (m=w', r=h)
    k_att_softmax<<<PIXn/4,256,0,stream>>>(ATT);
    k_pv<<<Bn*96,256,0,stream>>>(Vb, ATT, t, o, nullptr, gma, 0);   // out_w + resid
    k_transpose_b<<<Bn*Cn,256,0,stream>>>(Vb, Vb);                  // V -> V^T
    k_pv<<<Bn*96,256,0,stream>>>(Vb, ATT, nullptr, nullptr, Vb, gma, 1); // out_h^T over V^T
    k_merge<<<Bn*Cn,256,0,stream>>>(o, Vb);                         // o += (out_h^T)^T
  };

  cross(W1, W1);          // y1 = cross(t1), in place
  cross(W2, W2);          // y2 = cross(t2), in place (in d_out)
  k_add<<<147456,256,0,stream>>>(W1, W2);   // W1 = y1 + y2
  cross(W1, out);         // final
}

// Round 5
// 1301.475 us; speedup vs baseline: 12.9113x; 1.3806x over previous
//
#include <hip/hip_runtime.h>
#include <math.h>

#define Bn 16
#define Cn 256
#define CQn 32
#define CMn 128
#define Hn 96
#define Wn 96
#define Nn 9216
#define PIXn 147456

typedef short bf8 __attribute__((ext_vector_type(8)));
typedef float f32x4 __attribute__((ext_vector_type(4)));
#define MFMA(a,b,c) __builtin_amdgcn_mfma_f32_16x16x32_bf16(a,b,c,0,0,0)

typedef unsigned short ushort_t;

__device__ inline ushort_t f2bf(float f){
  union{float f; unsigned int u;} v; v.f=f;
  unsigned int r = v.u + 0x7fffu + ((v.u>>16)&1u);
  return (ushort_t)(r>>16);
}
__device__ inline float bf2f(ushort_t s){
  union{unsigned int u; float f;} v; v.u = ((unsigned int)s)<<16;
  return v.f;
}

__device__ inline float waveSum(float v){
#pragma unroll
  for(int o=32;o;o>>=1) v += __shfl_down(v,o,64);
  return v;
}
__device__ inline float waveMax(float v){
#pragma unroll
  for(int o=32;o;o>>=1) v = fmaxf(v,__shfl_down(v,o,64));
  return v;
}

// ---------------- gating: 3 passes over x ----------------

// pass1: block (cg, b), 1024 thr. xmean rows + mraw partials (wqr dot).
__global__ __launch_bounds__(1024) void k_pass1(const float* __restrict__ x,
    const float* __restrict__ wqr, float* __restrict__ xmean,
    float* __restrict__ partp){
  int cg = blockIdx.x, b = blockIdx.y, tid = threadIdx.x;
  __shared__ float r16[16];
  float mp[9];
#pragma unroll
  for(int k=0;k<9;k++) mp[k]=0.f;
  for(int cc=0;cc<16;cc++){
    int c = cg*16+cc;
    const float* row = x + ((size_t)b*Cn + c)*Nn;
    float w = wqr[c];
    float s = 0.f;
#pragma unroll
    for(int k=0;k<9;k++){
      float v = row[k*1024+tid];
      s += v;
      mp[k] += w*v;
    }
    s = waveSum(s);
    if((tid&63)==0) r16[tid>>6]=s;
    __syncthreads();
    if(tid==0){
      float t=0.f;
      for(int i=0;i<16;i++) t+=r16[i];
      xmean[(size_t)b*Cn + c] = t*(1.f/Nn);
    }
    __syncthreads();
  }
  float* dst = partp + ((size_t)cg*Bn + b)*Nn;
#pragma unroll
  for(int k=0;k<9;k++) dst[k*1024+tid]=mp[k];
}

// pass2: xw (maskb-weighted row sums) + craw partials (wvec dot)
__global__ __launch_bounds__(1024) void k_pass2(const float* __restrict__ x,
    const float* __restrict__ wvec, const float* __restrict__ maskb,
    float* __restrict__ xw, float* __restrict__ partp){
  int cg = blockIdx.x, b = blockIdx.y, tid = threadIdx.x;
  __shared__ float r16[16];
  float cp[9], mk[9];
#pragma unroll
  for(int k=0;k<9;k++){
    cp[k]=0.f;
    mk[k]=maskb[(size_t)b*Nn + k*1024+tid];
  }
  for(int cc=0;cc<16;cc++){
    int c = cg*16+cc;
    const float* row = x + ((size_t)b*Cn + c)*Nn;
    float w = wvec[(size_t)b*Cn + c];
    float s = 0.f;
#pragma unroll
    for(int k=0;k<9;k++){
      float v = row[k*1024+tid];
      s += mk[k]*v;
      cp[k] += w*v;
    }
    s = waveSum(s);
    if((tid&63)==0) r16[tid>>6]=s;
    __syncthreads();
    if(tid==0){
      float t=0.f;
      for(int i=0;i<16;i++) t+=r16[i];
      xw[(size_t)b*Cn + c] = t;
    }
    __syncthreads();
  }
  float* dst = partp + ((size_t)cg*Bn + b)*Nn;
#pragma unroll
  for(int k=0;k<9;k++) dst[k*1024+tid]=cp[k];
}

// sum 16 partial planes
__global__ void k_red16(const float* __restrict__ part, float* __restrict__ out){
  size_t p = (size_t)blockIdx.x*256 + threadIdx.x;
  float s=0.f;
#pragma unroll
  for(int cg=0;cg<16;cg++) s += part[(size_t)cg*Bn*Nn + p];
  out[p]=s;
}

__global__ void k_small1(const float* __restrict__ xmean, const float* __restrict__ wql,
                         const float* __restrict__ wvl, float* __restrict__ wvec){
  int b=blockIdx.x, t=threadIdx.x;
  __shared__ float xm[Cn];
  __shared__ float av[CMn];
  xm[t] = xmean[b*Cn+t];
  __syncthreads();
  if(t<CMn){
    float s=0.f;
    for(int c=0;c<Cn;c++) s += wql[t*Cn+c]*xm[c];
    av[t]=s;
  }
  __syncthreads();
  float s=0.f;
  for(int m=0;m<CMn;m++) s += av[m]*wvl[m*Cn+t];
  wvec[b*Cn+t]=s;
}

__global__ void k_softmax_n(const float* __restrict__ in, float* __restrict__ out, int mode){
  int b=blockIdx.x, tid=threadIdx.x, lane=tid&63, wid=tid>>6;
  const float* p = in + (size_t)b*Nn;
  __shared__ float red[16];
  __shared__ float bc2[2];
  float mx=-3e38f;
  for(int i=tid;i<Nn;i+=1024) mx=fmaxf(mx,p[i]);
  mx = waveMax(mx);
  if(lane==0) red[wid]=mx;
  __syncthreads();
  if(tid==0){ float m=red[0]; for(int i=1;i<16;i++) m=fmaxf(m,red[i]); bc2[0]=m; }
  __syncthreads();
  mx=bc2[0];
  float s=0.f;
  for(int i=tid;i<Nn;i+=1024) s+=expf(p[i]-mx);
  s = waveSum(s);
  __syncthreads();
  if(lane==0) red[wid]=s;
  __syncthreads();
  if(tid==0){ float t=0.f; for(int i=0;i<16;i++) t+=red[i]; bc2[1]=t; }
  __syncthreads();
  float inv=1.f/bc2[1];
  for(int i=tid;i<Nn;i+=1024){
    float e=expf(p[i]-mx)*inv;
    out[(size_t)b*Nn+i] = mode ? 1.f/(1.f+expf(-e)) : e;
  }
}

__global__ void k_small2(const float* __restrict__ xw, const float* __restrict__ wvr,
                         const float* __restrict__ wup, const float* __restrict__ bup,
                         float* __restrict__ g1){
  int b=blockIdx.x, t=threadIdx.x;
  __shared__ float xs[Cn];
  __shared__ float cx[CMn];
  xs[t]=xw[b*Cn+t];
  __syncthreads();
  if(t<CMn){
    float s=0.f;
    for(int c=0;c<Cn;c++) s += wvr[t*Cn+c]*xs[c];
    cx[t]=s;
  }
  __syncthreads();
  float s=bup[t];
  for(int m=0;m<CMn;m++) s += wup[t*CMn+m]*cx[m];
  g1[b*Cn+t]=1.f/(1.f+expf(-s));
}

// t1 = x*g1[b,c]; t2 = x*m2[b,n]  (bf16 out)
__global__ void k_gates(const float* __restrict__ x, const float* __restrict__ g1,
                        const float* __restrict__ m2, ushort_t* __restrict__ t1,
                        ushort_t* __restrict__ t2){
  size_t i4 = ((size_t)blockIdx.x*256 + threadIdx.x)*4;
  int n  = (int)(i4 % Nn);
  int bc = (int)(i4 / Nn);
  int b  = bc / Cn;
  float4 xv = *(const float4*)&x[i4];
  float g = g1[bc];
  float4 mv = *(const float4*)&m2[(size_t)b*Nn + n];
  uint2 a, c;
  a.x = (unsigned)f2bf(xv.x*g) | ((unsigned)f2bf(xv.y*g)<<16);
  a.y = (unsigned)f2bf(xv.z*g) | ((unsigned)f2bf(xv.w*g)<<16);
  c.x = (unsigned)f2bf(xv.x*mv.x) | ((unsigned)f2bf(xv.y*mv.y)<<16);
  c.y = (unsigned)f2bf(xv.z*mv.z) | ((unsigned)f2bf(xv.w*mv.w)<<16);
  *(uint2*)&t1[i4] = a;
  *(uint2*)&t2[i4] = c;
}

// a += b (bf16)
__global__ void k_add_bf(ushort_t* __restrict__ a, const ushort_t* __restrict__ b){
  size_t i = ((size_t)blockIdx.x*256 + threadIdx.x)*8;
  uint4 av = *(const uint4*)&a[i];
  uint4 bv = *(const uint4*)&b[i];
  unsigned* ap = (unsigned*)&av; unsigned* bp2 = (unsigned*)&bv;
  uint4 ov;
  unsigned* op = (unsigned*)&ov;
#pragma unroll
  for(int k=0;k<4;k++){
    float lo = bf2f((ushort_t)(ap[k]&0xffff)) + bf2f((ushort_t)(bp2[k]&0xffff));
    float hi = bf2f((ushort_t)(ap[k]>>16))    + bf2f((ushort_t)(bp2[k]>>16));
    op[k] = (unsigned)f2bf(lo) | ((unsigned)f2bf(hi)<<16);
  }
  *(uint4*)&a[i] = ov;
}

// ---------------- cross-attention, MFMA ----------------

__global__ void k_packb(const float* __restrict__ wq, const float* __restrict__ bq,
                        const float* __restrict__ wk, const float* __restrict__ bk,
                        const float* __restrict__ wv, const float* __restrict__ bv,
                        ushort_t* __restrict__ Wp, float* __restrict__ bp){
  int o = blockIdx.x, t = threadIdx.x;
  const float* src; float bs;
  if(o<32){ src = wq + o*Cn; bs = bq[o]; }
  else if(o<64){ src = wk + (o-32)*Cn; bs = bk[o-32]; }
  else { src = wv + (o-64)*Cn; bs = bv[o-64]; }
  Wp[o*Cn+t] = f2bf(src[t]);
  if(t==0) bp[o] = bs;
}

#define AP 40    // k_e / gemm W-tile row pitch
#define BP 264   // gemm Bt row pitch

// fused QKV GEMM (MFMA), bf16 in / bf16 out
__global__ __launch_bounds__(256) void k_gemm_qkv(const ushort_t* __restrict__ x,
    const ushort_t* __restrict__ Wp, const float* __restrict__ bp,
    ushort_t* __restrict__ Yqk, ushort_t* __restrict__ Vb){
  __shared__ ushort_t Ws[320*AP];
  __shared__ ushort_t Bt[64*BP];
  int b  = blockIdx.y;
  int n0 = blockIdx.x*64;
  int tid = threadIdx.x, lane = tid&63, wid = tid>>6;

  {
    const ushort_t* xb = x + (size_t)b*Cn*Nn + n0 + (tid&63);
    int cg = (tid>>6)*8;
#pragma unroll
    for(int p=0;p<8;p++){
      int c8 = p*32 + cg;
      unsigned e0=xb[(size_t)(c8+0)*Nn], e1=xb[(size_t)(c8+1)*Nn];
      unsigned e2=xb[(size_t)(c8+2)*Nn], e3=xb[(size_t)(c8+3)*Nn];
      unsigned e4=xb[(size_t)(c8+4)*Nn], e5=xb[(size_t)(c8+5)*Nn];
      unsigned e6=xb[(size_t)(c8+6)*Nn], e7=xb[(size_t)(c8+7)*Nn];
      uint4 pk;
      pk.x = e0 | (e1<<16); pk.y = e2 | (e3<<16);
      pk.z = e4 | (e5<<16); pk.w = e6 | (e7<<16);
      *(uint4*)&Bt[(tid&63)*BP + c8] = pk;
    }
  }

  f32x4 acc[5][4];
#pragma unroll
  for(int f=0;f<5;f++)
#pragma unroll
    for(int g=0;g<4;g++) acc[f][g] = (f32x4){0.f,0.f,0.f,0.f};

  for(int ki=0;ki<8;ki++){
    __syncthreads();
#pragma unroll
    for(int q=0;q<5;q++){
      int fidx = q*256 + tid;
      int o = fidx>>2, kk = (fidx&3)*8;
      uint4 wv = *(const uint4*)&Wp[o*Cn + ki*32 + kk];
      *(uint4*)&Ws[o*AP + kk] = wv;
    }
    __syncthreads();
    bf8 bfr[4];
#pragma unroll
    for(int g=0;g<4;g++)
      bfr[g] = *(const bf8*)&Bt[(g*16 + (lane&15))*BP + ki*32 + (lane>>4)*8];
#pragma unroll
    for(int f=0;f<5;f++){
      bf8 a = *(const bf8*)&Ws[(wid*80 + f*16 + (lane&15))*AP + (lane>>4)*8];
#pragma unroll
      for(int g=0;g<4;g++) acc[f][g] = MFMA(a, bfr[g], acc[f][g]);
    }
  }

#pragma unroll
  for(int f=0;f<5;f++){
    int ob = wid*80 + f*16 + (lane>>4)*4;
#pragma unroll
    for(int i=0;i<4;i++){
      int o = ob + i;
      float bias = bp[o];
      ushort_t* dst = (o<64) ? (Yqk + ((size_t)b*64 + o)*Nn)
                             : (Vb + ((size_t)b*Cn + (o-64))*Nn);
#pragma unroll
      for(int g=0;g<4;g++)
        dst[n0 + g*16 + (lane&15)] = f2bf(acc[f][g][i] + bias);
    }
  }
}

// per-plane 96x96 bf16 transpose, in-place safe
__global__ __launch_bounds__(256) void k_transpose_b(const ushort_t* __restrict__ src,
                                                     ushort_t* __restrict__ dst){
  __shared__ ushort_t Ls[96*98];
  size_t base = (size_t)blockIdx.x * Nn;
  int tid = threadIdx.x;
  for(int e=tid*2; e<Nn; e+=512){
    unsigned int u = *(const unsigned int*)&src[base+e];
    int r=e/96, c=e%96;
    *(unsigned int*)&Ls[r*98+c] = u;
  }
  __syncthreads();
  for(int e=tid*2; e<Nn; e+=512){
    int r=e/96, c=e%96;
    unsigned int u = (unsigned int)Ls[c*98+r] | (((unsigned int)Ls[(c+1)*98+r])<<16);
    *(unsigned int*)&dst[base+e] = u;
  }
}

// QK^T (MFMA): block (b,r). att[(b*Nn + m*pm + r*pr)*192 + aoff + n]
__global__ __launch_bounds__(256) void k_e(const ushort_t* __restrict__ Y,
    float* __restrict__ att, int aoff, int diag, int pm, int pr){
  __shared__ ushort_t Qt[96*AP];
  __shared__ ushort_t Kt[96*AP];
  int bid = blockIdx.x; int b = bid/96, r = bid%96;
  int tid = threadIdx.x, lane = tid&63, wid = tid>>6;
  {
    int half = tid>>7;
    int cg   = (tid>>5)&3;
    int l32  = tid&31;
    ushort_t* T = half ? Kt : Qt;
    const ushort_t* S = Y + ((size_t)b*64 + half*32 + cg*8)*Nn + (size_t)r*96;
#pragma unroll
    for(int p=0;p<3;p++){
      int sp = p*32 + l32;
      unsigned e0=S[(size_t)0*Nn+sp], e1=S[(size_t)1*Nn+sp];
      unsigned e2=S[(size_t)2*Nn+sp], e3=S[(size_t)3*Nn+sp];
      unsigned e4=S[(size_t)4*Nn+sp], e5=S[(size_t)5*Nn+sp];
      unsigned e6=S[(size_t)6*Nn+sp], e7=S[(size_t)7*Nn+sp];
      uint4 pk;
      pk.x = e0 | (e1<<16); pk.y = e2 | (e3<<16);
      pk.z = e4 | (e5<<16); pk.w = e6 | (e7<<16);
      *(uint4*)&T[sp*AP + cg*8] = pk;
    }
  }
  __syncthreads();
  int mb = (wid>>1)*48, nb = (wid&1)*48;
  const f32x4 z4 = {0.f,0.f,0.f,0.f};
  f32x4 acc[3][3];
  bf8 a[3], bb[3];
#pragma unroll
  for(int f=0;f<3;f++) a[f] = *(const bf8*)&Qt[(mb+f*16+(lane&15))*AP + (lane>>4)*8];
#pragma unroll
  for(int g=0;g<3;g++) bb[g] = *(const bf8*)&Kt[(nb+g*16+(lane&15))*AP + (lane>>4)*8];
#pragma unroll
  for(int f=0;f<3;f++)
#pragma unroll
    for(int g=0;g<3;g++) acc[f][g] = MFMA(a[f], bb[g], z4);
#pragma unroll
  for(int f=0;f<3;f++)
#pragma unroll
    for(int i=0;i<4;i++){
      int m = mb + f*16 + (lane>>4)*4 + i;
      float* arow = att + ((size_t)b*Nn + (size_t)m*pm + (size_t)r*pr)*192 + aoff;
#pragma unroll
      for(int g=0;g<3;g++){
        int n = nb + g*16 + (lane&15);
        arow[n] = (diag && n==m) ? -1e30f : acc[f][g][i];
      }
    }
}

// softmax over 192: fp32 logits in, bf16 normalized out
__global__ void k_softmax_att(const float* __restrict__ att, ushort_t* __restrict__ attb){
  int wave = threadIdx.x>>6, lane = threadIdx.x&63;
  size_t p = (size_t)blockIdx.x*4 + wave;
  const float* a = att + p*192;
  float v0=a[lane], v1=a[lane+64], v2=a[lane+128];
  float mx = fmaxf(v0, fmaxf(v1,v2));
#pragma unroll
  for(int o=32;o;o>>=1) mx = fmaxf(mx, __shfl_xor(mx,o,64));
  float e0=expf(v0-mx), e1=expf(v1-mx), e2=expf(v2-mx);
  float s=e0+e1+e2;
#pragma unroll
  for(int o=32;o;o>>=1) s += __shfl_xor(s,o,64);
  float inv=1.f/s;
  ushort_t* ob = attb + p*192;
  ob[lane]     = f2bf(e0*inv);
  ob[lane+64]  = f2bf(e1*inv);
  ob[lane+128] = f2bf(e2*inv);
}

#define SP 120   // att-tile row pitch (2-way bank aliasing = free)

// PV (MFMA). Block (r, chalf, b): O[c][n] = gm*sum_j V[c][r*96+j]*A[n][j]
// MODE 0 (pvw): A from attb[...,96+j], adds bf16 resid; MODE 1 (pvh): A from attb[...,j]
// OUTF 1: fp32 out (final cross), else bf16 out.
template<int MODE, int OUTF>
__global__ __launch_bounds__(256) void k_pv(const ushort_t* V,
    const ushort_t* __restrict__ attb, const ushort_t* resid,
    float* __restrict__ Of, ushort_t* Ob, const float* __restrict__ gp){
  __shared__ ushort_t As[96*SP];
  int r = blockIdx.x, ch2 = blockIdx.y, b = blockIdx.z;
  float gm = gp[0];
  int tid = threadIdx.x, lane = tid&63, wid = tid>>6;
  size_t vbase = (size_t)b*Cn*Nn + (size_t)r*96;
  // prefetch V fragments (before barrier; hides HBM latency under staging)
  bf8 vf[6];
#pragma unroll
  for(int f=0;f<2;f++)
#pragma unroll
    for(int j=0;j<3;j++)
      vf[f*3+j] = *(const bf8*)&V[vbase
        + (size_t)(ch2*128 + wid*32 + f*16 + (lane&15))*Nn + j*32 + (lane>>4)*8];
  // stage att slice (bf16, 16B copies)
  const ushort_t* ab = attb + (size_t)b*Nn*192
                     + (MODE ? (size_t)r*192 : (size_t)r*96*192 + 96);
  const size_t arow = MODE ? (size_t)96*192 : (size_t)192;
  for(int u=tid; u<96*12; u+=256){
    int n=u/12, j8=(u%12)*8;
    uint4 q = *(const uint4*)&ab[(size_t)n*arow + j8];
    *(uint4*)&As[n*SP + j8] = q;
  }
  __syncthreads();
  f32x4 acc[2][6];
#pragma unroll
  for(int f=0;f<2;f++)
#pragma unroll
    for(int g=0;g<6;g++) acc[f][g] = (f32x4){0.f,0.f,0.f,0.f};
#pragma unroll
  for(int j0=0;j0<3;j0++){
    bf8 bfr[6];
#pragma unroll
    for(int g=0;g<6;g++)
      bfr[g] = *(const bf8*)&As[(g*16+(lane&15))*SP + j0*32 + (lane>>4)*8];
#pragma unroll
    for(int f=0;f<2;f++)
#pragma unroll
      for(int g=0;g<6;g++) acc[f][g] = MFMA(vf[f*3+j0], bfr[g], acc[f][g]);
  }
#pragma unroll
  for(int f=0;f<2;f++){
    int cb = ch2*128 + wid*32 + f*16 + (lane>>4)*4;
#pragma unroll
    for(int i=0;i<4;i++){
      size_t row = vbase + (size_t)(cb+i)*Nn;
#pragma unroll
      for(int g=0;g<6;g++){
        int n = g*16 + (lane&15);
        float val = gm*acc[f][g][i];
        if(MODE==0) val += bf2f(resid[row+n]);
        if(OUTF) Of[row+n] = val;
        else     Ob[row+n] = f2bf(val);
      }
    }
  }
}

// out += (OT)^T per (b,c) plane
template<int OUTF>
__global__ __launch_bounds__(256) void k_merge(float* __restrict__ outf,
    ushort_t* __restrict__ outb, const ushort_t* __restrict__ OT){
  __shared__ ushort_t Ls[96*98];
  size_t base = (size_t)blockIdx.x * Nn;
  int tid = threadIdx.x;
  for(int e=tid*2; e<Nn; e+=512){
    unsigned int u = *(const unsigned int*)&OT[base+e];
    int r=e/96, c=e%96;
    *(unsigned int*)&Ls[r*98+c] = u;
  }
  __syncthreads();
  for(int e=tid*4; e<Nn; e+=1024){
    int r=e/96, c=e%96;
    if(OUTF){
      float4 o = *(float4*)&outf[base+e];
      o.x += bf2f(Ls[(c+0)*98+r]); o.y += bf2f(Ls[(c+1)*98+r]);
      o.z += bf2f(Ls[(c+2)*98+r]); o.w += bf2f(Ls[(c+3)*98+r]);
      *(float4*)&outf[base+e] = o;
    } else {
      uint2 u = *(uint2*)&outb[base+e];
      float a0 = bf2f((ushort_t)(u.x&0xffff)) + bf2f(Ls[(c+0)*98+r]);
      float a1 = bf2f((ushort_t)(u.x>>16))    + bf2f(Ls[(c+1)*98+r]);
      float a2 = bf2f((ushort_t)(u.y&0xffff)) + bf2f(Ls[(c+2)*98+r]);
      float a3 = bf2f((ushort_t)(u.y>>16))    + bf2f(Ls[(c+3)*98+r]);
      u.x = (unsigned)f2bf(a0) | ((unsigned)f2bf(a1)<<16);
      u.y = (unsigned)f2bf(a2) | ((unsigned)f2bf(a3)<<16);
      *(uint2*)&outb[base+e] = u;
    }
  }
}

extern "C" void kernel_launch(void* const* d_in, const int* in_sizes, int n_in,
                              void* d_out, int out_size, void* d_ws, size_t ws_size,
                              hipStream_t stream){
  const float* x    = (const float*)d_in[0];
  const float* wqr  = (const float*)d_in[1];
  const float* wvr  = (const float*)d_in[2];
  const float* wup  = (const float*)d_in[3];
  const float* bup  = (const float*)d_in[4];
  const float* wql  = (const float*)d_in[5];
  const float* wvl  = (const float*)d_in[6];
  const float* crwq = (const float*)d_in[7];
  const float* crbq = (const float*)d_in[8];
  const float* crwk = (const float*)d_in[9];
  const float* crbk = (const float*)d_in[10];
  const float* crwv = (const float*)d_in[11];
  const float* crbv = (const float*)d_in[12];
  const float* gma  = (const float*)d_in[13];
  float* out = (float*)d_out;

  const size_t XSZ = (size_t)Bn*Cn*Nn;    // 37,748,736
  const size_t YSZ = (size_t)Bn*64*Nn;    //  9,437,184
  char* wsb = (char*)d_ws;
  ushort_t* T1   = (ushort_t*)wsb; wsb += XSZ*2;
  ushort_t* T2   = (ushort_t*)wsb; wsb += XSZ*2;
  ushort_t* Vb   = (ushort_t*)wsb; wsb += XSZ*2;
  ushort_t* Yqk  = (ushort_t*)wsb; wsb += YSZ*2;
  ushort_t* Yqkt = (ushort_t*)wsb; wsb += YSZ*2;
  float*    ATT  = (float*)wsb;    wsb += (size_t)PIXn*192*4;
  ushort_t* ATTb = (ushort_t*)wsb; wsb += (size_t)PIXn*192*2;
  float*    partp= (float*)wsb;    wsb += (size_t)16*Bn*Nn*4;
  ushort_t* Wpb  = (ushort_t*)wsb; wsb += 320*Cn*2;
  float*    bp   = (float*)wsb;    wsb += 320*4;
  float*    xmean= (float*)wsb;    wsb += Bn*Cn*4;
  float*    wvec = (float*)wsb;    wsb += Bn*Cn*4;
  float*    xw   = (float*)wsb;    wsb += Bn*Cn*4;
  float*    g1   = (float*)wsb;    wsb += Bn*Cn*4;
  float*    mraw = (float*)wsb;    wsb += (size_t)PIXn*4;
  float*    maskb= (float*)wsb;    wsb += (size_t)PIXn*4;
  float*    craw = (float*)wsb;    wsb += (size_t)PIXn*4;
  float*    m2   = (float*)wsb;    wsb += (size_t)PIXn*4;

  k_packb<<<320,256,0,stream>>>(crwq,crbq,crwk,crbk,crwv,crbv,Wpb,bp);

  // ---- gating (3 x-passes) ----
  k_pass1<<<dim3(16,Bn),1024,0,stream>>>(x, wqr, xmean, partp);
  k_red16<<<Bn*Nn/256,256,0,stream>>>(partp, mraw);
  k_small1<<<Bn,256,0,stream>>>(xmean, wql, wvl, wvec);
  k_softmax_n<<<Bn,1024,0,stream>>>(mraw, maskb, 0);
  k_pass2<<<dim3(16,Bn),1024,0,stream>>>(x, wvec, maskb, xw, partp);
  k_red16<<<Bn*Nn/256,256,0,stream>>>(partp, craw);
  k_softmax_n<<<Bn,1024,0,stream>>>(craw, m2, 1);
  k_small2<<<Bn,256,0,stream>>>(xw, wvr, wup, bup, g1);
  k_gates<<<XSZ/1024,256,0,stream>>>(x, g1, m2, T1, T2);

  auto cross = [&](const ushort_t* t, ushort_t* ob, float* of, int finalf){
    k_gemm_qkv<<<dim3(Nn/64,Bn),256,0,stream>>>(t, Wpb, bp, Yqk, Vb);
    k_transpose_b<<<Bn*64,256,0,stream>>>(Yqk, Yqkt);
    k_e<<<Bn*96,256,0,stream>>>(Yqkt, ATT, 0, 1, 96, 1);   // e_h
    k_e<<<Bn*96,256,0,stream>>>(Yqk,  ATT, 96, 0, 1, 96);  // e_w
    k_softmax_att<<<PIXn/4,256,0,stream>>>(ATT, ATTb);
    if(finalf) k_pv<0,1><<<dim3(96,2,Bn),256,0,stream>>>(Vb, ATTb, t, of, nullptr, gma);
    else       k_pv<0,0><<<dim3(96,2,Bn),256,0,stream>>>(Vb, ATTb, t, nullptr, ob, gma);
    k_transpose_b<<<Bn*Cn,256,0,stream>>>(Vb, Vb);          // V -> V^T
    k_pv<1,0><<<dim3(96,2,Bn),256,0,stream>>>(Vb, ATTb, nullptr, nullptr, Vb, gma);
    if(finalf) k_merge<1><<<Bn*Cn,256,0,stream>>>(of, nullptr, Vb);
    else       k_merge<0><<<Bn*Cn,256,0,stream>>>(nullptr, ob, Vb);
  };

  cross(T1, T1, nullptr, 0);      // y1 in T1 (bf16, in place)
  cross(T2, T2, nullptr, 0);      // y2 in T2
  k_add_bf<<<XSZ/2048,256,0,stream>>>(T1, T2);   // T1 = y1+y2
  cross(T1, nullptr, out, 1);     // final, fp32 into d_out
}

// Round 6
// 1221.718 us; speedup vs baseline: 13.7542x; 1.0653x over previous
//
#include <hip/hip_runtime.h>
#include <math.h>

#define Bn 16
#define Cn 256
#define CQn 32
#define CMn 128
#define Hn 96
#define Wn 96
#define Nn 9216
#define PIXn 147456

typedef short bf8 __attribute__((ext_vector_type(8)));
typedef float f32x4 __attribute__((ext_vector_type(4)));
#define MFMA(a,b,c) __builtin_amdgcn_mfma_f32_16x16x32_bf16(a,b,c,0,0,0)

typedef unsigned short ushort_t;

__device__ inline ushort_t f2bf(float f){
  union{float f; unsigned int u;} v; v.f=f;
  unsigned int r = v.u + 0x7fffu + ((v.u>>16)&1u);
  return (ushort_t)(r>>16);
}
__device__ inline float bf2f(ushort_t s){
  union{unsigned int u; float f;} v; v.u = ((unsigned int)s)<<16;
  return v.f;
}

__device__ inline float waveSum(float v){
#pragma unroll
  for(int o=32;o;o>>=1) v += __shfl_down(v,o,64);
  return v;
}
__device__ inline float waveMax(float v){
#pragma unroll
  for(int o=32;o;o>>=1) v = fmaxf(v,__shfl_down(v,o,64));
  return v;
}

// ---------------- gating: 3 passes over x ----------------

__global__ __launch_bounds__(1024) void k_pass1(const float* __restrict__ x,
    const float* __restrict__ wqr, float* __restrict__ xmean,
    float* __restrict__ partp){
  int cg = blockIdx.x, b = blockIdx.y, tid = threadIdx.x;
  __shared__ float r16[16];
  float mp[9];
#pragma unroll
  for(int k=0;k<9;k++) mp[k]=0.f;
  for(int cc=0;cc<16;cc++){
    int c = cg*16+cc;
    const float* row = x + ((size_t)b*Cn + c)*Nn;
    float w = wqr[c];
    float s = 0.f;
#pragma unroll
    for(int k=0;k<9;k++){
      float v = row[k*1024+tid];
      s += v;
      mp[k] += w*v;
    }
    s = waveSum(s);
    if((tid&63)==0) r16[tid>>6]=s;
    __syncthreads();
    if(tid==0){
      float t=0.f;
      for(int i=0;i<16;i++) t+=r16[i];
      xmean[(size_t)b*Cn + c] = t*(1.f/Nn);
    }
    __syncthreads();
  }
  float* dst = partp + ((size_t)cg*Bn + b)*Nn;
#pragma unroll
  for(int k=0;k<9;k++) dst[k*1024+tid]=mp[k];
}

__global__ __launch_bounds__(1024) void k_pass2(const float* __restrict__ x,
    const float* __restrict__ wvec, const float* __restrict__ maskb,
    float* __restrict__ xw, float* __restrict__ partp){
  int cg = blockIdx.x, b = blockIdx.y, tid = threadIdx.x;
  __shared__ float r16[16];
  float cp[9], mk[9];
#pragma unroll
  for(int k=0;k<9;k++){
    cp[k]=0.f;
    mk[k]=maskb[(size_t)b*Nn + k*1024+tid];
  }
  for(int cc=0;cc<16;cc++){
    int c = cg*16+cc;
    const float* row = x + ((size_t)b*Cn + c)*Nn;
    float w = wvec[(size_t)b*Cn + c];
    float s = 0.f;
#pragma unroll
    for(int k=0;k<9;k++){
      float v = row[k*1024+tid];
      s += mk[k]*v;
      cp[k] += w*v;
    }
    s = waveSum(s);
    if((tid&63)==0) r16[tid>>6]=s;
    __syncthreads();
    if(tid==0){
      float t=0.f;
      for(int i=0;i<16;i++) t+=r16[i];
      xw[(size_t)b*Cn + c] = t;
    }
    __syncthreads();
  }
  float* dst = partp + ((size_t)cg*Bn + b)*Nn;
#pragma unroll
  for(int k=0;k<9;k++) dst[k*1024+tid]=cp[k];
}

__global__ void k_red16(const float* __restrict__ part, float* __restrict__ out){
  size_t p = (size_t)blockIdx.x*256 + threadIdx.x;
  float s=0.f;
#pragma unroll
  for(int cg=0;cg<16;cg++) s += part[(size_t)cg*Bn*Nn + p];
  out[p]=s;
}

__global__ void k_small1(const float* __restrict__ xmean, const float* __restrict__ wql,
                         const float* __restrict__ wvl, float* __restrict__ wvec){
  int b=blockIdx.x, t=threadIdx.x;
  __shared__ float xm[Cn];
  __shared__ float av[CMn];
  xm[t] = xmean[b*Cn+t];
  __syncthreads();
  if(t<CMn){
    float s=0.f;
    for(int c=0;c<Cn;c++) s += wql[t*Cn+c]*xm[c];
    av[t]=s;
  }
  __syncthreads();
  float s=0.f;
  for(int m=0;m<CMn;m++) s += av[m]*wvl[m*Cn+t];
  wvec[b*Cn+t]=s;
}

__global__ void k_softmax_n(const float* __restrict__ in, float* __restrict__ out, int mode){
  int b=blockIdx.x, tid=threadIdx.x, lane=tid&63, wid=tid>>6;
  const float* p = in + (size_t)b*Nn;
  __shared__ float red[16];
  __shared__ float bc2[2];
  float mx=-3e38f;
  for(int i=tid;i<Nn;i+=1024) mx=fmaxf(mx,p[i]);
  mx = waveMax(mx);
  if(lane==0) red[wid]=mx;
  __syncthreads();
  if(tid==0){ float m=red[0]; for(int i=1;i<16;i++) m=fmaxf(m,red[i]); bc2[0]=m; }
  __syncthreads();
  mx=bc2[0];
  float s=0.f;
  for(int i=tid;i<Nn;i+=1024) s+=expf(p[i]-mx);
  s = waveSum(s);
  __syncthreads();
  if(lane==0) red[wid]=s;
  __syncthreads();
  if(tid==0){ float t=0.f; for(int i=0;i<16;i++) t+=red[i]; bc2[1]=t; }
  __syncthreads();
  float inv=1.f/bc2[1];
  for(int i=tid;i<Nn;i+=1024){
    float e=expf(p[i]-mx)*inv;
    out[(size_t)b*Nn+i] = mode ? 1.f/(1.f+expf(-e)) : e;
  }
}

__global__ void k_small2(const float* __restrict__ xw, const float* __restrict__ wvr,
                         const float* __restrict__ wup, const float* __restrict__ bup,
                         float* __restrict__ g1){
  int b=blockIdx.x, t=threadIdx.x;
  __shared__ float xs[Cn];
  __shared__ float cx[CMn];
  xs[t]=xw[b*Cn+t];
  __syncthreads();
  if(t<CMn){
    float s=0.f;
    for(int c=0;c<Cn;c++) s += wvr[t*Cn+c]*xs[c];
    cx[t]=s;
  }
  __syncthreads();
  float s=bup[t];
  for(int m=0;m<CMn;m++) s += wup[t*CMn+m]*cx[m];
  g1[b*Cn+t]=1.f/(1.f+expf(-s));
}

__global__ void k_gates(const float* __restrict__ x, const float* __restrict__ g1,
                        const float* __restrict__ m2, ushort_t* __restrict__ t1,
                        ushort_t* __restrict__ t2){
  size_t i4 = ((size_t)blockIdx.x*256 + threadIdx.x)*4;
  int n  = (int)(i4 % Nn);
  int bc = (int)(i4 / Nn);
  int b  = bc / Cn;
  float4 xv = *(const float4*)&x[i4];
  float g = g1[bc];
  float4 mv = *(const float4*)&m2[(size_t)b*Nn + n];
  uint2 a, c;
  a.x = (unsigned)f2bf(xv.x*g) | ((unsigned)f2bf(xv.y*g)<<16);
  a.y = (unsigned)f2bf(xv.z*g) | ((unsigned)f2bf(xv.w*g)<<16);
  c.x = (unsigned)f2bf(xv.x*mv.x) | ((unsigned)f2bf(xv.y*mv.y)<<16);
  c.y = (unsigned)f2bf(xv.z*mv.z) | ((unsigned)f2bf(xv.w*mv.w)<<16);
  *(uint2*)&t1[i4] = a;
  *(uint2*)&t2[i4] = c;
}

// ---------------- cross-attention, MFMA ----------------

__global__ void k_packb(const float* __restrict__ wq, const float* __restrict__ bq,
                        const float* __restrict__ wk, const float* __restrict__ bk,
                        const float* __restrict__ wv, const float* __restrict__ bv,
                        ushort_t* __restrict__ Wp, float* __restrict__ bp){
  int o = blockIdx.x, t = threadIdx.x;
  const float* src; float bs;
  if(o<32){ src = wq + o*Cn; bs = bq[o]; }
  else if(o<64){ src = wk + (o-32)*Cn; bs = bk[o-32]; }
  else { src = wv + (o-64)*Cn; bs = bv[o-64]; }
  Wp[o*Cn+t] = f2bf(src[t]);
  if(t==0) bp[o] = bs;
}

#define AP 40
#define BP 264

__global__ __launch_bounds__(256) void k_gemm_qkv(const ushort_t* __restrict__ x,
    const ushort_t* __restrict__ Wp, const float* __restrict__ bp,
    ushort_t* __restrict__ Yqk, ushort_t* __restrict__ Vb){
  __shared__ ushort_t Ws[320*AP];
  __shared__ ushort_t Bt[64*BP];
  int b  = blockIdx.y;
  int n0 = blockIdx.x*64;
  int tid = threadIdx.x, lane = tid&63, wid = tid>>6;

  {
    const ushort_t* xb = x + (size_t)b*Cn*Nn + n0 + (tid&63);
    int cg = (tid>>6)*8;
#pragma unroll
    for(int p=0;p<8;p++){
      int c8 = p*32 + cg;
      unsigned e0=xb[(size_t)(c8+0)*Nn], e1=xb[(size_t)(c8+1)*Nn];
      unsigned e2=xb[(size_t)(c8+2)*Nn], e3=xb[(size_t)(c8+3)*Nn];
      unsigned e4=xb[(size_t)(c8+4)*Nn], e5=xb[(size_t)(c8+5)*Nn];
      unsigned e6=xb[(size_t)(c8+6)*Nn], e7=xb[(size_t)(c8+7)*Nn];
      uint4 pk;
      pk.x = e0 | (e1<<16); pk.y = e2 | (e3<<16);
      pk.z = e4 | (e5<<16); pk.w = e6 | (e7<<16);
      *(uint4*)&Bt[(tid&63)*BP + c8] = pk;
    }
  }

  f32x4 acc[5][4];
#pragma unroll
  for(int f=0;f<5;f++)
#pragma unroll
    for(int g=0;g<4;g++) acc[f][g] = (f32x4){0.f,0.f,0.f,0.f};

  for(int ki=0;ki<8;ki++){
    __syncthreads();
#pragma unroll
    for(int q=0;q<5;q++){
      int fidx = q*256 + tid;
      int o = fidx>>2, kk = (fidx&3)*8;
      uint4 wv = *(const uint4*)&Wp[o*Cn + ki*32 + kk];
      *(uint4*)&Ws[o*AP + kk] = wv;
    }
    __syncthreads();
    bf8 bfr[4];
#pragma unroll
    for(int g=0;g<4;g++)
      bfr[g] = *(const bf8*)&Bt[(g*16 + (lane&15))*BP + ki*32 + (lane>>4)*8];
#pragma unroll
    for(int f=0;f<5;f++){
      bf8 a = *(const bf8*)&Ws[(wid*80 + f*16 + (lane&15))*AP + (lane>>4)*8];
#pragma unroll
      for(int g=0;g<4;g++) acc[f][g] = MFMA(a, bfr[g], acc[f][g]);
    }
  }

#pragma unroll
  for(int f=0;f<5;f++){
    int ob = wid*80 + f*16 + (lane>>4)*4;
#pragma unroll
    for(int i=0;i<4;i++){
      int o = ob + i;
      float bias = bp[o];
      ushort_t* dst = (o<64) ? (Yqk + ((size_t)b*64 + o)*Nn)
                             : (Vb + ((size_t)b*Cn + (o-64))*Nn);
#pragma unroll
      for(int g=0;g<4;g++)
        dst[n0 + g*16 + (lane&15)] = f2bf(acc[f][g][i] + bias);
    }
  }
}

// per-plane 96x96 bf16 transpose (in- or out-of-place)
__global__ __launch_bounds__(256) void k_transpose_b(const ushort_t* __restrict__ src,
                                                     ushort_t* __restrict__ dst){
  __shared__ ushort_t Ls[96*98];
  size_t base = (size_t)blockIdx.x * Nn;
  int tid = threadIdx.x;
  for(int e=tid*2; e<Nn; e+=512){
    unsigned int u = *(const unsigned int*)&src[base+e];
    int r=e/96, c=e%96;
    *(unsigned int*)&Ls[r*98+c] = u;
  }
  __syncthreads();
  for(int e=tid*2; e<Nn; e+=512){
    int r=e/96, c=e%96;
    unsigned int u = (unsigned int)Ls[c*98+r] | (((unsigned int)Ls[(c+1)*98+r])<<16);
    *(unsigned int*)&dst[base+e] = u;
  }
}

// unified QK^T: blockIdx.y==0 -> e_h (Yqkt, diag, pixel=m*96+r), ==1 -> e_w (Yqk, pixel=r*96+m)
__global__ __launch_bounds__(256) void k_e2(const ushort_t* __restrict__ Yqk,
    const ushort_t* __restrict__ Yqkt, float* __restrict__ att){
  __shared__ ushort_t Qt[96*AP];
  __shared__ ushort_t Kt[96*AP];
  int r = blockIdx.x, mode = blockIdx.y, b = blockIdx.z;
  const ushort_t* Y = mode ? Yqk : Yqkt;
  int aoff = mode ? 96 : 0;
  int pm   = mode ? 1  : 96;
  int pr   = mode ? 96 : 1;
  int tid = threadIdx.x, lane = tid&63, wid = tid>>6;
  {
    int half = tid>>7;
    int cg   = (tid>>5)&3;
    int l32  = tid&31;
    ushort_t* T = half ? Kt : Qt;
    const ushort_t* S = Y + ((size_t)b*64 + half*32 + cg*8)*Nn + (size_t)r*96;
#pragma unroll
    for(int p=0;p<3;p++){
      int sp = p*32 + l32;
      unsigned e0=S[(size_t)0*Nn+sp], e1=S[(size_t)1*Nn+sp];
      unsigned e2=S[(size_t)2*Nn+sp], e3=S[(size_t)3*Nn+sp];
      unsigned e4=S[(size_t)4*Nn+sp], e5=S[(size_t)5*Nn+sp];
      unsigned e6=S[(size_t)6*Nn+sp], e7=S[(size_t)7*Nn+sp];
      uint4 pk;
      pk.x = e0 | (e1<<16); pk.y = e2 | (e3<<16);
      pk.z = e4 | (e5<<16); pk.w = e6 | (e7<<16);
      *(uint4*)&T[sp*AP + cg*8] = pk;
    }
  }
  __syncthreads();
  int mb = (wid>>1)*48, nb = (wid&1)*48;
  const f32x4 z4 = {0.f,0.f,0.f,0.f};
  f32x4 acc[3][3];
  bf8 a[3], bb[3];
#pragma unroll
  for(int f=0;f<3;f++) a[f] = *(const bf8*)&Qt[(mb+f*16+(lane&15))*AP + (lane>>4)*8];
#pragma unroll
  for(int g=0;g<3;g++) bb[g] = *(const bf8*)&Kt[(nb+g*16+(lane&15))*AP + (lane>>4)*8];
#pragma unroll
  for(int f=0;f<3;f++)
#pragma unroll
    for(int g=0;g<3;g++) acc[f][g] = MFMA(a[f], bb[g], z4);
  int diag = (mode==0);
#pragma unroll
  for(int f=0;f<3;f++)
#pragma unroll
    for(int i=0;i<4;i++){
      int m = mb + f*16 + (lane>>4)*4 + i;
      float* arow = att + ((size_t)b*Nn + (size_t)m*pm + (size_t)r*pr)*192 + aoff;
#pragma unroll
      for(int g=0;g<3;g++){
        int n = nb + g*16 + (lane&15);
        arow[n] = (diag && n==m) ? -1e30f : acc[f][g][i];
      }
    }
}

// softmax over 192; writes split bf16 buffers:
//   attw[b][h*96+w][j] = sm[96+j] ; atth[b][w*96+h][k] = sm[k]
__global__ void k_softmax_att(const float* __restrict__ att,
    ushort_t* __restrict__ attw, ushort_t* __restrict__ atth){
  int wave = threadIdx.x>>6, lane = threadIdx.x&63;
  int p = blockIdx.x*4 + wave;
  const float* a = att + (size_t)p*192;
  float v0=a[lane], v1=a[lane+64], v2=a[lane+128];
  float mx = fmaxf(v0, fmaxf(v1,v2));
#pragma unroll
  for(int o=32;o;o>>=1) mx = fmaxf(mx, __shfl_xor(mx,o,64));
  float e0=expf(v0-mx), e1=expf(v1-mx), e2=expf(v2-mx);
  float s=e0+e1+e2;
#pragma unroll
  for(int o=32;o;o>>=1) s += __shfl_xor(s,o,64);
  float inv=1.f/s;
  int b = p/Nn, rem = p%Nn, h = rem/96, w = rem%96;
  ushort_t* ph = atth + ((size_t)b*Nn + (size_t)w*96 + h)*96;
  ushort_t* pw = attw + (size_t)p*96;
  ph[lane] = f2bf(e0*inv);
  if(lane<32) ph[64+lane] = f2bf(e1*inv);
  else        pw[lane-32] = f2bf(e1*inv);
  pw[lane+32] = f2bf(e2*inv);
}

#define SP 120

// unified PV: blockIdx.y==0 -> pvw (Vb, attw, +resid -> Of/OwB)
//             blockIdx.y==1 -> pvh (VT, atth, -> OT in place over VT)
template<int OUTF>
__global__ __launch_bounds__(512) void k_pv2(const ushort_t* __restrict__ Vb,
    const ushort_t* __restrict__ VT, const ushort_t* __restrict__ attw,
    const ushort_t* __restrict__ atth, const ushort_t* resid,
    float* __restrict__ Of, ushort_t* OwB, ushort_t* OT,
    const float* __restrict__ gp){
  __shared__ ushort_t As[96*SP];
  int r = blockIdx.x, mode = blockIdx.y, b = blockIdx.z;
  float gm = gp[0];
  int tid = threadIdx.x, lane = tid&63, wid = tid>>6;
  const ushort_t* V = mode ? VT : Vb;
  size_t vbase = (size_t)b*Cn*Nn + (size_t)r*96;
  // prefetch all V fragments for this block's 256 channels
  bf8 vf[6];
#pragma unroll
  for(int f=0;f<2;f++)
#pragma unroll
    for(int j=0;j<3;j++)
      vf[f*3+j] = *(const bf8*)&V[vbase
        + (size_t)(wid*32 + f*16 + (lane&15))*Nn + j*32 + (lane>>4)*8];
  // stage att slice: both modes read contiguous [row][96] layout
  const ushort_t* ab = (mode ? atth : attw) + ((size_t)b*Nn + (size_t)r*96)*96;
  for(int u=tid; u<96*12; u+=512){
    int n=u/12, j8=(u%12)*8;
    uint4 q = *(const uint4*)&ab[n*96 + j8];
    *(uint4*)&As[n*SP + j8] = q;
  }
  __syncthreads();
  f32x4 acc[2][6];
#pragma unroll
  for(int f=0;f<2;f++)
#pragma unroll
    for(int g=0;g<6;g++) acc[f][g] = (f32x4){0.f,0.f,0.f,0.f};
#pragma unroll
  for(int j0=0;j0<3;j0++){
    bf8 bfr[6];
#pragma unroll
    for(int g=0;g<6;g++)
      bfr[g] = *(const bf8*)&As[(g*16+(lane&15))*SP + j0*32 + (lane>>4)*8];
#pragma unroll
    for(int f=0;f<2;f++)
#pragma unroll
      for(int g=0;g<6;g++) acc[f][g] = MFMA(vf[f*3+j0], bfr[g], acc[f][g]);
  }
#pragma unroll
  for(int f=0;f<2;f++){
    int cb = wid*32 + f*16 + (lane>>4)*4;
#pragma unroll
    for(int i=0;i<4;i++){
      size_t row = vbase + (size_t)(cb+i)*Nn;
      if(mode){
#pragma unroll
        for(int g=0;g<6;g++){
          int n = g*16 + (lane&15);
          OT[row+n] = f2bf(gm*acc[f][g][i]);
        }
      } else {
#pragma unroll
        for(int g=0;g<6;g++){
          int n = g*16 + (lane&15);
          float val = gm*acc[f][g][i] + bf2f(resid[row+n]);
          if(OUTF) Of[row+n] = val;
          else     OwB[row+n] = f2bf(val);
        }
      }
    }
  }
}

// merge: VAR 0: outb += OT^T ; VAR 1: outf += OT^T ; VAR 2: outb += add + OT^T
template<int VAR>
__global__ __launch_bounds__(256) void k_merge(float* __restrict__ outf,
    ushort_t* __restrict__ outb, const ushort_t* __restrict__ add,
    const ushort_t* __restrict__ OT){
  __shared__ ushort_t Ls[96*98];
  size_t base = (size_t)blockIdx.x * Nn;
  int tid = threadIdx.x;
  for(int e=tid*2; e<Nn; e+=512){
    unsigned int u = *(const unsigned int*)&OT[base+e];
    int r=e/96, c=e%96;
    *(unsigned int*)&Ls[r*98+c] = u;
  }
  __syncthreads();
  for(int e=tid*4; e<Nn; e+=1024){
    int r=e/96, c=e%96;
    float t0 = bf2f(Ls[(c+0)*98+r]), t1 = bf2f(Ls[(c+1)*98+r]);
    float t2 = bf2f(Ls[(c+2)*98+r]), t3 = bf2f(Ls[(c+3)*98+r]);
    if(VAR==1){
      float4 o = *(float4*)&outf[base+e];
      o.x += t0; o.y += t1; o.z += t2; o.w += t3;
      *(float4*)&outf[base+e] = o;
    } else {
      uint2 u = *(uint2*)&outb[base+e];
      float a0 = bf2f((ushort_t)(u.x&0xffff)) + t0;
      float a1 = bf2f((ushort_t)(u.x>>16))    + t1;
      float a2 = bf2f((ushort_t)(u.y&0xffff)) + t2;
      float a3 = bf2f((ushort_t)(u.y>>16))    + t3;
      if(VAR==2){
        uint2 v = *(const uint2*)&add[base+e];
        a0 += bf2f((ushort_t)(v.x&0xffff));
        a1 += bf2f((ushort_t)(v.x>>16));
        a2 += bf2f((ushort_t)(v.y&0xffff));
        a3 += bf2f((ushort_t)(v.y>>16));
      }
      u.x = (unsigned)f2bf(a0) | ((unsigned)f2bf(a1)<<16);
      u.y = (unsigned)f2bf(a2) | ((unsigned)f2bf(a3)<<16);
      *(uint2*)&outb[base+e] = u;
    }
  }
}

extern "C" void kernel_launch(void* const* d_in, const int* in_sizes, int n_in,
                              void* d_out, int out_size, void* d_ws, size_t ws_size,
                              hipStream_t stream){
  const float* x    = (const float*)d_in[0];
  const float* wqr  = (const float*)d_in[1];
  const float* wvr  = (const float*)d_in[2];
  const float* wup  = (const float*)d_in[3];
  const float* bup  = (const float*)d_in[4];
  const float* wql  = (const float*)d_in[5];
  const float* wvl  = (const float*)d_in[6];
  const float* crwq = (const float*)d_in[7];
  const float* crbq = (const float*)d_in[8];
  const float* crwk = (const float*)d_in[9];
  const float* crbk = (const float*)d_in[10];
  const float* crwv = (const float*)d_in[11];
  const float* crbv = (const float*)d_in[12];
  const float* gma  = (const float*)d_in[13];
  float* out = (float*)d_out;

  const size_t XSZ = (size_t)Bn*Cn*Nn;
  const size_t YSZ = (size_t)Bn*64*Nn;
  char* wsb = (char*)d_ws;
  ushort_t* T1   = (ushort_t*)wsb; wsb += XSZ*2;
  ushort_t* T2   = (ushort_t*)wsb; wsb += XSZ*2;
  ushort_t* Vb   = (ushort_t*)wsb; wsb += XSZ*2;
  ushort_t* Yqk  = (ushort_t*)wsb; wsb += YSZ*2;
  ushort_t* Yqkt = (ushort_t*)wsb; wsb += YSZ*2;
  float*    ATT  = (float*)wsb;    wsb += (size_t)PIXn*192*4;
  ushort_t* VT   = (ushort_t*)ATT;      // aliases ATT: live only after softmax
  ushort_t* ATTw = (ushort_t*)wsb; wsb += (size_t)PIXn*96*2;
  ushort_t* ATTh = (ushort_t*)wsb; wsb += (size_t)PIXn*96*2;
  float*    partp= (float*)wsb;    wsb += (size_t)16*Bn*Nn*4;
  ushort_t* Wpb  = (ushort_t*)wsb; wsb += 320*Cn*2;
  float*    bp   = (float*)wsb;    wsb += 320*4;
  float*    xmean= (float*)wsb;    wsb += Bn*Cn*4;
  float*    wvec = (float*)wsb;    wsb += Bn*Cn*4;
  float*    xw   = (float*)wsb;    wsb += Bn*Cn*4;
  float*    g1   = (float*)wsb;    wsb += Bn*Cn*4;
  float*    mraw = (float*)wsb;    wsb += (size_t)PIXn*4;
  float*    maskb= (float*)wsb;    wsb += (size_t)PIXn*4;
  float*    craw = (float*)wsb;    wsb += (size_t)PIXn*4;
  float*    m2   = (float*)wsb;    wsb += (size_t)PIXn*4;

  k_packb<<<320,256,0,stream>>>(crwq,crbq,crwk,crbk,crwv,crbv,Wpb,bp);

  // ---- gating ----
  k_pass1<<<dim3(16,Bn),1024,0,stream>>>(x, wqr, xmean, partp);
  k_red16<<<Bn*Nn/256,256,0,stream>>>(partp, mraw);
  k_small1<<<Bn,256,0,stream>>>(xmean, wql, wvl, wvec);
  k_softmax_n<<<Bn,1024,0,stream>>>(mraw, maskb, 0);
  k_pass2<<<dim3(16,Bn),1024,0,stream>>>(x, wvec, maskb, xw, partp);
  k_red16<<<Bn*Nn/256,256,0,stream>>>(partp, craw);
  k_softmax_n<<<Bn,1024,0,stream>>>(craw, m2, 1);
  k_small2<<<Bn,256,0,stream>>>(xw, wvr, wup, bup, g1);
  k_gates<<<XSZ/1024,256,0,stream>>>(x, g1, m2, T1, T2);

  // var: 0 = plain bf16 cross (in place), 2 = bf16 cross + merge-add into T1,
  //      1 = final cross (fp32 out)
  auto cross = [&](const ushort_t* t, ushort_t* ob, float* of, int var){
    k_gemm_qkv<<<dim3(Nn/64,Bn),256,0,stream>>>(t, Wpb, bp, Yqk, Vb);
    k_transpose_b<<<Bn*64,256,0,stream>>>(Yqk, Yqkt);
    k_e2<<<dim3(96,2,Bn),256,0,stream>>>(Yqk, Yqkt, ATT);
    k_softmax_att<<<PIXn/4,256,0,stream>>>(ATT, ATTw, ATTh);
    k_transpose_b<<<Bn*Cn,256,0,stream>>>(Vb, VT);     // ATT dead; VT reuses it
    if(var==1) k_pv2<1><<<dim3(96,2,Bn),512,0,stream>>>(Vb, VT, ATTw, ATTh, t, of, nullptr, VT, gma);
    else       k_pv2<0><<<dim3(96,2,Bn),512,0,stream>>>(Vb, VT, ATTw, ATTh, t, nullptr, ob, VT, gma);
    if(var==0)      k_merge<0><<<Bn*Cn,256,0,stream>>>(nullptr, ob, nullptr, VT);
    else if(var==1) k_merge<1><<<Bn*Cn,256,0,stream>>>(of, nullptr, nullptr, VT);
    else            k_merge<2><<<Bn*Cn,256,0,stream>>>(nullptr, T1, T2, VT);
  };

  cross(T1, T1, nullptr, 0);      // y1 in T1
  cross(T2, T2, nullptr, 2);      // y2; merge adds T2 + pvh^T into T1
  cross(T1, nullptr, out, 1);     // final, fp32 into d_out
}